// Round 20
// baseline (279.002 us; speedup 1.0000x reference)
//
#include <hip/hip_runtime.h>
#include <math.h>

#define H_    8
#define DK_   32
#define NT_   6
#define ET_   3
#define DIM_  256
#define LN_EPS 1e-5f
#define NMATS (NT_ * 7)   // per node type: Q, Kt[0..2], Vt[0..2]
#define NBIN  (ET_ * H_)  // 24
#define NSTEP 56          // 7 matrices x 8 K-slabs
#define TROWS 128         // rows per projection tile
#define MAXNB 1024        // max 256-thread blocks over n
#define ESB   1024        // blocks for fused escatter+score
#define PACKN (NMATS * 8 * 16 * 64)
#define BIASN (NMATS * 256)

typedef __attribute__((ext_vector_type(8))) short short8v;
typedef __attribute__((ext_vector_type(4))) float f32x4;
typedef __attribute__((ext_vector_type(2))) float f32x2;

__device__ __forceinline__ unsigned short f2bf(float f){
    unsigned u = __float_as_uint(f);
    return (unsigned short)((u + 0x7fffu + ((u >> 16) & 1u)) >> 16);
}
__device__ __forceinline__ float bflo(unsigned u){ return __uint_as_float(u << 16); }
__device__ __forceinline__ float bfhi(unsigned u){ return __uint_as_float(u & 0xFFFF0000u); }
__device__ __forceinline__ float bf2f(unsigned short v){ return __uint_as_float((unsigned)v << 16); }

// fp8 e4m3 via HW converter (self-consistent encode/decode on gfx950)
__device__ __forceinline__ unsigned char f2fp8(float f){
    int r = __builtin_amdgcn_cvt_pk_fp8_f32(f, f, 0, false);
    return (unsigned char)(r & 0xFF);
}

// ---------------- node hist + edge target count (fused) ----------------
__global__ __launch_bounds__(256) void k_histcount(
    const int* __restrict__ ntyp, int n, int* __restrict__ bhist, int nb,
    const int* __restrict__ ei, int E_, int* __restrict__ ecnt)
{
    const int tid = threadIdx.x;
    if ((int)blockIdx.x < nb){
        const int gi = blockIdx.x * 256 + tid;
        const int wave = tid >> 6, lane = tid & 63;
        const int t = (gi < n) ? ntyp[gi] : -1;
        __shared__ int whist[4][8];
        #pragma unroll
        for (int tt = 0; tt < NT_; tt++){
            unsigned long long bal = __ballot(t == tt);
            if (lane == 0) whist[wave][tt] = __popcll(bal);
        }
        __syncthreads();
        if (tid < NT_)
            bhist[blockIdx.x * 8 + tid] =
                whist[0][tid] + whist[1][tid] + whist[2][tid] + whist[3][tid];
    }
    // edge target counting, grid-stride
    for (int e = blockIdx.x * 256 + tid; e < E_; e += ESB * 256)
        atomicAdd(&ecnt[ei[E_ + e]], 1);
}

// single block; ALL dependent chains run against LDS, never global.
__global__ __launch_bounds__(256) void k_scanhist(int* __restrict__ bhist, int nb,
                                                  int* __restrict__ offs, int* __restrict__ meta){
    __shared__ int hh[MAXNB * 8 / 4];
    __shared__ int tot[8], toff[8], tbase[8], ntl_s;
    const int tid = threadIdx.x;

    for (int i = tid; i < nb * 8; i += 256) hh[i] = bhist[i];
    __syncthreads();

    if (tid < 8){
        int run = 0;
        for (int b = 0; b < nb; b++){
            int c = hh[b * 8 + tid];
            hh[b * 8 + tid] = run;
            run += c;
        }
        tot[tid] = run;
    }
    __syncthreads();

    if (tid == 0){
        int off = 0, tb = 0;
        for (int tt = 0; tt < NT_; tt++){
            toff[tt] = off;
            tbase[tt] = tb;
            tb += (tot[tt] + TROWS - 1) / TROWS;
            off += tot[tt];
        }
        for (int tt = NT_; tt < 8; tt++){ toff[tt] = 0; tbase[tt] = tb; }
        ntl_s = tb;
        meta[0] = tb;
    }
    __syncthreads();

    for (int i = tid; i < ntl_s; i += 256){
        int t = 0;
        #pragma unroll
        for (int tt = 1; tt < NT_; tt++) if (i >= tbase[tt]) t = tt;
        const int k = i - tbase[t];
        const int rem = tot[t] - k * TROWS;
        meta[1 + 3*i]     = t;
        meta[1 + 3*i + 1] = toff[t] + k * TROWS;
        meta[1 + 3*i + 2] = (rem < TROWS) ? rem : TROWS;
    }
    if (tid < NT_) offs[tid] = toff[tid];

    for (int i = tid; i < nb * 8; i += 256)
        bhist[i] = hh[i] + toff[i & 7];
}

// node rank-scatter + edge-count block scan (fused; both per-256-chunk)
__global__ __launch_bounds__(256) void k_scatscan(
    const int* __restrict__ ntyp, int n, const int* __restrict__ bhist,
    int* __restrict__ sorted,
    const int* __restrict__ ecnt, int* __restrict__ eoff, int* __restrict__ bsum)
{
    const int tid = threadIdx.x;
    const int gi = blockIdx.x * 256 + tid;
    const int wave = tid >> 6, lane = tid & 63;
    // --- scatter2 ---
    const int t = (gi < n) ? ntyp[gi] : -1;
    __shared__ int whist[4][8];
    unsigned long long mybal = 0;
    #pragma unroll
    for (int tt = 0; tt < NT_; tt++){
        unsigned long long bal = __ballot(t == tt);
        if (lane == 0) whist[wave][tt] = __popcll(bal);
        if (t == tt) mybal = bal;
    }
    __syncthreads();
    if (gi < n){
        int wo = 0;
        for (int w = 0; w < wave; w++) wo += whist[w][t];
        const unsigned long long below = (lane == 0) ? 0ULL : (~0ULL >> (64 - lane));
        const int rank = bhist[blockIdx.x * 8 + t] + wo + __popcll(mybal & below);
        sorted[rank] = gi;
    }
    // --- scan1 on ecnt ---
    __shared__ int sh[256];
    int v = (gi < n) ? ecnt[gi] : 0;
    __syncthreads();
    sh[tid] = v;
    __syncthreads();
    for (int off = 1; off < 256; off <<= 1){
        int tv = (tid >= off) ? sh[tid - off] : 0;
        __syncthreads();
        sh[tid] += tv;
        __syncthreads();
    }
    if (gi < n) eoff[gi] = sh[tid] - v;
    if (tid == 255) bsum[blockIdx.x] = sh[255];
}

// ---------------- weight fuse + MFMA-fragment pack + bias (fused) ----------------
__global__ __launch_bounds__(256) void k_packbias(
    const float* __restrict__ Wq, const float* __restrict__ Wk, const float* __restrict__ Wv,
    const float* __restrict__ Wa, const float* __restrict__ Wm, const float* __restrict__ pri,
    const float* __restrict__ bq, const float* __restrict__ bk, const float* __restrict__ bv,
    unsigned short* __restrict__ pw, float* __restrict__ bpack)
{
    const int gid0 = blockIdx.x * 256 + threadIdx.x;
    if (gid0 < PACKN){
        const int gid = gid0;
        const int l = gid & 63;
        const int j = (gid >> 6) & 15;
        const int p = (gid >> 10) & 7;
        const int matg = gid >> 13;
        const int tn = matg / 7, m = matg % 7;
        const int col = j * 16 + (l & 15);
        const int k0  = p * 32 + (l >> 4) * 8;
        const int h = col >> 5, c = col & 31;

        float vals[8];
        if (m == 0){
            #pragma unroll
            for (int i = 0; i < 8; i++)
                vals[i] = Wq[((size_t)tn * 256 + (k0 + i)) * 256 + col];
        } else if (m <= 3){
            const int te = m - 1;
            const float scale = 0.17677669529663687f * pri[te * H_ + h];
            #pragma unroll
            for (int i = 0; i < 8; i++){
                const float* wk = Wk + ((size_t)tn * 256 + (k0 + i)) * 256 + h * 32;
                const float* wa = Wa + (size_t)te * 1024 + c;
                float s = 0.f;
                for (int d = 0; d < 32; d++) s = fmaf(wk[d], wa[d * 32], s);
                vals[i] = s * scale;
            }
        } else {
            const int te = m - 4;
            #pragma unroll
            for (int i = 0; i < 8; i++){
                const float* wv = Wv + ((size_t)tn * 256 + (k0 + i)) * 256 + h * 32;
                const float* wm = Wm + (size_t)te * 1024 + c;
                float s = 0.f;
                for (int d = 0; d < 32; d++) s = fmaf(wv[d], wm[d * 32], s);
                vals[i] = s;
            }
        }
        unsigned short o[8];
        #pragma unroll
        for (int i = 0; i < 8; i++) o[i] = f2bf(vals[i]);
        *reinterpret_cast<uint4*>(pw + (size_t)gid * 8) = *reinterpret_cast<const uint4*>(o);
    } else if (gid0 < PACKN + BIASN){
        const int gid = gid0 - PACKN;
        const int col = gid & 255;
        const int matg = gid >> 8;
        const int tn = matg / 7, m = matg % 7;
        const int h = col >> 5, c = col & 31;
        float v;
        if (m == 0) v = bq[tn * 256 + col];
        else if (m <= 3){
            const int te = m - 1;
            float s = 0.f;
            for (int d = 0; d < 32; d++) s = fmaf(bk[tn * 256 + h * 32 + d], Wa[te * 1024 + d * 32 + c], s);
            v = s * 0.17677669529663687f * pri[te * H_ + h];
        } else {
            const int te = m - 4;
            float s = 0.f;
            for (int d = 0; d < 32; d++) s = fmaf(bv[tn * 256 + h * 32 + d], Wm[te * 1024 + d * 32 + c], s);
            v = s;
        }
        bpack[gid] = v;
    }
}

// ---------------- MFMA grouped projection (7 matrices; Q->bf16, Kt/Vt->fp8) ----------------
__global__ __launch_bounds__(512, 2) void k_proj(
    const float* __restrict__ x, const int* __restrict__ sorted, const int* __restrict__ meta,
    const unsigned short* __restrict__ pw, const float* __restrict__ bpack,
    unsigned short* __restrict__ Qb, unsigned char* __restrict__ Ktb, unsigned char* __restrict__ Vtb)
{
    const int ntl = meta[0];
    if ((int)blockIdx.x >= ntl) return;
    const int q = ntl >> 3, r = ntl & 7;
    const int xcd = blockIdx.x & 7, ii = blockIdx.x >> 3;
    const int tile = (xcd < r) ? xcd * (q + 1) + ii
                               : r * (q + 1) + (xcd - r) * q + ii;
    const int tn    = meta[1 + 3*tile];
    const int start = meta[1 + 3*tile + 1];
    const int rows  = meta[1 + 3*tile + 2];

    __shared__ unsigned short xs[TROWS * 256];
    __shared__ int ids[TROWS];
    const int tid = threadIdx.x;
    if (tid < TROWS) ids[tid] = sorted[start + ((tid < rows) ? tid : 0)];
    __syncthreads();

    char* xb = reinterpret_cast<char*>(xs);
    for (int idx = tid; idx < TROWS * 32; idx += 512){
        const int r2 = idx >> 5, c16 = idx & 31;
        const float* src = x + (size_t)ids[r2] * DIM_ + c16 * 8;
        float4 a = *reinterpret_cast<const float4*>(src);
        float4 b = *reinterpret_cast<const float4*>(src + 4);
        unsigned short o[8] = {f2bf(a.x), f2bf(a.y), f2bf(a.z), f2bf(a.w),
                               f2bf(b.x), f2bf(b.y), f2bf(b.z), f2bf(b.w)};
        const int byte = r2 * 512 + ((c16 * 16) ^ ((r2 & 7) << 4));
        *reinterpret_cast<uint4*>(xb + byte) = *reinterpret_cast<const uint4*>(o);
    }
    __syncthreads();   // xs read-only from here on; NO barriers in the main loop

    const int wid = tid >> 6, l = tid & 63;
    const int rg = wid >> 2;
    const int cg = wid & 3;
    const int l15 = l & 15, lg = l >> 4;
    const int xorv = (l15 & 7) << 4;
    const size_t matbase = (size_t)tn * 7;
    const int rowbase = rg * 64;

    f32x4 acc[4][4];
    short8v b0[4], b1[4];

    {
        const unsigned short* sp0 = pw + matbase * 8 * 8192;
        #pragma unroll
        for (int j = 0; j < 4; j++)
            b0[j] = *reinterpret_cast<const short8v*>(sp0 + (cg * 4 + j) * 512 + l * 8);
    }

    auto proj_step = [&](const int s, short8v (&cur)[4], short8v (&pf)[4]){
        const int m = s >> 3, p = s & 7;
        const int matg = (int)matbase + m;

        if (s + 1 < NSTEP){
            const unsigned short* sp = pw + (matbase * 8 + (s + 1)) * 8192;
            #pragma unroll
            for (int j = 0; j < 4; j++)
                pf[j] = *reinterpret_cast<const short8v*>(sp + (cg * 4 + j) * 512 + l * 8);
        }

        if (p == 0){
            #pragma unroll
            for (int j = 0; j < 4; j++){
                const float bj = bpack[matg * 256 + cg * 64 + j * 16 + l15];
                #pragma unroll
                for (int i = 0; i < 4; i++) acc[i][j] = (f32x4){bj, bj, bj, bj};
            }
        }

        {
            short8v a[4];
            const int kb = (p * 64 + (lg << 4)) ^ xorv;
            #pragma unroll
            for (int i = 0; i < 4; i++)
                a[i] = *reinterpret_cast<const short8v*>(xb + (rowbase + i * 16 + l15) * 512 + kb);
            #pragma unroll
            for (int i = 0; i < 4; i++)
                #pragma unroll
                for (int j = 0; j < 4; j++)
                    acc[i][j] = __builtin_amdgcn_mfma_f32_16x16x32_bf16(a[i], cur[j], acc[i][j], 0, 0, 0);
        }

        if (p == 7){
            #pragma unroll
            for (int i = 0; i < 4; i++){
                #pragma unroll
                for (int rr = 0; rr < 4; rr++){
                    const int row = rowbase + i * 16 + lg * 4 + rr;
                    if (row < rows){
                        const size_t node = (size_t)ids[row];
                        if (m == 0){
                            unsigned short* optr = Qb + node * 256 + cg * 64 + l15;
                            #pragma unroll
                            for (int j = 0; j < 4; j++) optr[j * 16] = f2bf(acc[i][j][rr]);
                        } else {
                            unsigned char* optr = ((m <= 3) ? Ktb + node * 768 + (size_t)(m - 1) * 256
                                                            : Vtb + node * 768 + (size_t)(m - 4) * 256)
                                                  + cg * 64 + l15;
                            #pragma unroll
                            for (int j = 0; j < 4; j++) optr[j * 16] = f2fp8(acc[i][j][rr]);
                        }
                    }
                }
            }
        }
    };

    for (int s = 0; s < NSTEP; s += 2){
        proj_step(s,     b0, b1);
        proj_step(s + 1, b1, b0);
    }
}

// ---------------- remaining CSR scans ----------------
__global__ __launch_bounds__(256) void k_scan2(int* __restrict__ bsum, int nb){
    __shared__ int sh[MAXNB];
    const int tid = threadIdx.x;
    for (int i = tid; i < nb; i += 256) sh[i] = bsum[i];
    __syncthreads();
    if (tid == 0){
        int run = 0;
        for (int b = 0; b < nb; b++){ int c = sh[b]; sh[b] = run; run += c; }
    }
    __syncthreads();
    for (int i = tid; i < nb; i += 256) bsum[i] = sh[i];
}

__global__ __launch_bounds__(256) void k_scan3(int n, int E_, const int* __restrict__ bsum,
                                               int* __restrict__ eoff, int* __restrict__ cursor){
    const int gi = blockIdx.x * 256 + threadIdx.x;
    if (gi < n){
        int v = eoff[gi] + bsum[blockIdx.x];
        eoff[gi] = v;
        cursor[gi] = v;
    }
    if (gi == 0) eoff[n] = E_;
}

// ---------------- fused edge scatter + score + denominator partials ----------------
// thread per edge (grid-stride): place edge in CSR, compute 8 head scores
// (fp8 K row x bf16 Q row), write SC at CSR pos, accumulate per-(t,h) bins in LDS.
__global__ __launch_bounds__(256) void k_esc_score(
    const int* __restrict__ ei, const int* __restrict__ etyp, int E_,
    int* __restrict__ cursor,
    const unsigned char* __restrict__ Ktb, const unsigned short* __restrict__ Qb,
    int* __restrict__ ep, unsigned short* __restrict__ SC, float* __restrict__ psum)
{
    __shared__ float bins[NBIN];
    const int tid = threadIdx.x;
    if (tid < NBIN) bins[tid] = 0.f;
    __syncthreads();

    for (int e = blockIdx.x * 256 + tid; e < E_; e += ESB * 256){
        const int tg = ei[E_ + e];
        const int t  = etyp[e];
        const int s  = ei[e];
        const int pos = atomicAdd(&cursor[tg], 1);
        ep[pos] = s | (t << 28);
        const unsigned char*  kp = Ktb + ((size_t)s * 3 + t) * 256;
        const unsigned short* qp = Qb + (size_t)tg * 256;
        for (int h = 0; h < H_; h++){
            const unsigned char*  kh = kp + h * 32;
            const unsigned short* qh = qp + h * 32;
            uint4 k8a = *reinterpret_cast<const uint4*>(kh);
            uint4 k8b = *reinterpret_cast<const uint4*>(kh + 16);
            unsigned kw[8] = {k8a.x, k8a.y, k8a.z, k8a.w, k8b.x, k8b.y, k8b.z, k8b.w};
            uint4 qa = *reinterpret_cast<const uint4*>(qh);
            uint4 qb = *reinterpret_cast<const uint4*>(qh + 8);
            uint4 qc = *reinterpret_cast<const uint4*>(qh + 16);
            uint4 qd = *reinterpret_cast<const uint4*>(qh + 24);
            unsigned qw[16] = {qa.x, qa.y, qa.z, qa.w, qb.x, qb.y, qb.z, qb.w,
                               qc.x, qc.y, qc.z, qc.w, qd.x, qd.y, qd.z, qd.w};
            float acc = 0.f;
            #pragma unroll
            for (int w = 0; w < 8; w++){
                f32x2 lo = __builtin_amdgcn_cvt_pk_f32_fp8(kw[w], false);
                f32x2 hi = __builtin_amdgcn_cvt_pk_f32_fp8(kw[w], true);
                acc = fmaf(lo.x, bflo(qw[2*w]),   acc);
                acc = fmaf(lo.y, bfhi(qw[2*w]),   acc);
                acc = fmaf(hi.x, bflo(qw[2*w+1]), acc);
                acc = fmaf(hi.y, bfhi(qw[2*w+1]), acc);
            }
            const float ev = __expf(acc);
            SC[(size_t)pos * 8 + h] = f2bf(ev);
            atomicAdd(&bins[t * 8 + h], ev);
        }
    }
    __syncthreads();
    if (tid < NBIN) psum[blockIdx.x * NBIN + tid] = bins[tid];
}

__global__ __launch_bounds__(256) void k_redsum(const float* __restrict__ psum,
                                                float* __restrict__ rw){
    const int b = blockIdx.x, tid = threadIdx.x;
    float s = 0.f;
    for (int i = tid; i < ESB; i += 256) s += psum[i * NBIN + b];
    #pragma unroll
    for (int m = 1; m < 64; m <<= 1) s += __shfl_xor(s, m, 64);
    __shared__ float sm[4];
    if ((tid & 63) == 0) sm[tid >> 6] = s;
    __syncthreads();
    if (tid == 0){
        float t = sm[0] + sm[1] + sm[2] + sm[3];
        rw[b] = (t > 0.f) ? 1.f / t : 0.f;
    }
}

// ---------------- gather aggregation (fp8 Vt, thread per (tg,h)) + skip + LN ----------------
__global__ __launch_bounds__(256) void k_aggln(
    const unsigned char* __restrict__ Vtb, const float* __restrict__ x,
    const int* __restrict__ eoff, const int* __restrict__ ep,
    const unsigned short* __restrict__ SC, const float* __restrict__ rw,
    const float* __restrict__ g, const float* __restrict__ b,
    float* __restrict__ out, int n)
{
    const int idx = blockIdx.x * 256 + threadIdx.x;
    if (idx >= n * H_) return;
    const int tg = idx >> 3, h = idx & 7;

    const float rw0 = rw[h], rw1 = rw[8 + h], rw2 = rw[16 + h];

    float acc[DK_];
    #pragma unroll
    for (int k = 0; k < DK_; k++) acc[k] = 0.f;

    const int p1 = eoff[tg + 1];
    for (int pos = eoff[tg]; pos < p1; ++pos){
        const int pl = ep[pos];
        const int s = pl & 0x0FFFFFFF, t = pl >> 28;
        const float rwv = (t == 0) ? rw0 : (t == 1) ? rw1 : rw2;
        const float w = bf2f(SC[(size_t)pos * 8 + h]) * rwv;
        const unsigned char* vp = Vtb + ((size_t)s * 3 + t) * 256 + h * 32;  // 32 fp8
        uint4 v8a = *reinterpret_cast<const uint4*>(vp);
        uint4 v8b = *reinterpret_cast<const uint4*>(vp + 16);
        unsigned vw[8] = {v8a.x, v8a.y, v8a.z, v8a.w, v8b.x, v8b.y, v8b.z, v8b.w};
        #pragma unroll
        for (int q = 0; q < 8; q++){
            f32x2 lo = __builtin_amdgcn_cvt_pk_f32_fp8(vw[q], false);
            f32x2 hi = __builtin_amdgcn_cvt_pk_f32_fp8(vw[q], true);
            acc[4*q+0] = fmaf(w, lo.x, acc[4*q+0]);
            acc[4*q+1] = fmaf(w, lo.y, acc[4*q+1]);
            acc[4*q+2] = fmaf(w, hi.x, acc[4*q+2]);
            acc[4*q+3] = fmaf(w, hi.y, acc[4*q+3]);
        }
    }

    #pragma unroll
    for (int k4 = 0; k4 < 8; k4++){
        float4 x4 = *reinterpret_cast<const float4*>(x + (size_t)tg * DIM_ + h * DK_ + k4 * 4);
        acc[4*k4] += x4.x; acc[4*k4+1] += x4.y; acc[4*k4+2] += x4.z; acc[4*k4+3] += x4.w;
    }

    float s1 = 0.f, s2 = 0.f;
    #pragma unroll
    for (int k = 0; k < DK_; k++){ s1 += acc[k]; s2 = fmaf(acc[k], acc[k], s2); }
    #pragma unroll
    for (int m = 1; m <= 4; m <<= 1){
        s1 += __shfl_xor(s1, m, 64);
        s2 += __shfl_xor(s2, m, 64);
    }
    const float mu  = s1 * (1.f / DIM_);
    const float var = s2 * (1.f / DIM_) - mu * mu;
    const float rs  = rsqrtf(var + LN_EPS);

    float* __restrict__ o = out + (size_t)tg * DIM_ + h * DK_;
    #pragma unroll
    for (int k4 = 0; k4 < 8; k4++){
        float4 g4 = *reinterpret_cast<const float4*>(g + h * DK_ + k4 * 4);
        float4 b4 = *reinterpret_cast<const float4*>(b + h * DK_ + k4 * 4);
        float4 o4;
        o4.x = (acc[4*k4]   - mu) * rs * g4.x + b4.x;
        o4.y = (acc[4*k4+1] - mu) * rs * g4.y + b4.y;
        o4.z = (acc[4*k4+2] - mu) * rs * g4.z + b4.z;
        o4.w = (acc[4*k4+3] - mu) * rs * g4.w + b4.w;
        *reinterpret_cast<float4*>(o + k4 * 4) = o4;
    }
}

extern "C" void kernel_launch(void* const* d_in, const int* in_sizes, int n_in,
                              void* d_out, int out_size, void* d_ws, size_t ws_size,
                              hipStream_t stream)
{
    const float* x   = (const float*)d_in[0];
    const int*  ei   = (const int*)d_in[1];
    const int*  ntyp = (const int*)d_in[3];
    const int*  etyp = (const int*)d_in[4];
    const float* Wk  = (const float*)d_in[5];
    const float* bk  = (const float*)d_in[6];
    const float* Wq  = (const float*)d_in[7];
    const float* bq  = (const float*)d_in[8];
    const float* Wv  = (const float*)d_in[9];
    const float* bv  = (const float*)d_in[10];
    const float* pri = (const float*)d_in[11];
    const float* Wa  = (const float*)d_in[12];
    const float* Wm  = (const float*)d_in[13];
    const float* lg  = (const float*)d_in[14];
    const float* lb  = (const float*)d_in[15];

    const int n  = in_sizes[0] / DIM_;
    const int E_ = in_sizes[4];
    const int EH = E_ * H_;
    float* out = (float*)d_out;

    // ---- workspace layout ----
    const size_t NF = (size_t)n * DIM_;
    unsigned short* Qb  = (unsigned short*)d_ws;          // n*256 bf16 (raw Q)
    unsigned char*  Ktb = (unsigned char*)(Qb + NF);      // n*3*256 fp8 (K @ Wa[t], scaled)
    unsigned char*  Vtb = Ktb + NF * 3;                   // n*3*256 fp8 (V @ Wm[t])
    unsigned short* pwp = (unsigned short*)(Vtb + NF * 3);// NMATS*65536 bf16
    unsigned short* SC  = pwp + (size_t)NMATS * 65536;    // E*8 bf16 (CSR order, exp'd)
    float* bpack = (float*)(SC + (size_t)EH);             // NMATS*256
    float* psum  = bpack + NMATS * 256;                   // ESB*24
    float* rw    = psum + (size_t)ESB * NBIN;             // 24
    int* sorted  = (int*)(rw + NBIN);                     // n
    int* offsN   = sorted + n;                            // 8
    const int NB = (n + 255) / 256;
    int* bhist   = offsN + 8;                             // NB*8
    int* meta    = bhist + (size_t)NB * 8;                // 1 + 3*maxtiles
    const int maxtiles = (n + TROWS - 1) / TROWS + NT_;
    int* ecnt    = meta + 1 + 3 * maxtiles;               // n
    int* eoff    = ecnt + n;                              // n + 1
    int* cursorE = eoff + n + 1;                          // n
    int* bsum    = cursorE + n;                           // <= 1024
    int* ep      = bsum + 1024;                           // E (payload only)

    hipMemsetAsync(ecnt, 0, (size_t)n * sizeof(int), stream);

    // weight fuse/pack + bias (fused)
    k_packbias<<<(PACKN + BIASN + 255) / 256, 256, 0, stream>>>(
        Wq, Wk, Wv, Wa, Wm, pri, bq, bk, bv, pwp, bpack);

    // node hist + edge count (fused)
    k_histcount<<<ESB, 256, 0, stream>>>(ntyp, n, bhist, NB, ei, E_, ecnt);
    k_scanhist <<<1, 256, 0, stream>>>(bhist, NB, offsN, meta);
    k_scatscan <<<NB, 256, 0, stream>>>(ntyp, n, bhist, sorted, ecnt, eoff, bsum);
    k_scan2    <<<1, 256, 0, stream>>>(bsum, NB);
    k_scan3    <<<NB, 256, 0, stream>>>(n, E_, bsum, eoff, cursorE);

    // fused MFMA projections
    k_proj<<<maxtiles, 512, 0, stream>>>(x, sorted, meta, pwp, bpack, Qb, Ktb, Vtb);

    // fused edge scatter + scores + denominator partials
    k_esc_score<<<ESB, 256, 0, stream>>>(ei, etyp, E_, cursorE, Ktb, Qb, ep, SC, psum);
    k_redsum   <<<NBIN, 256, 0, stream>>>(psum, rw);
    k_aggln    <<<(n * H_ + 255) / 256, 256, 0, stream>>>(Vtb, x, eoff, ep, SC, rw, lg, lb, out, n);
}

// Round 21
// 239.806 us; speedup vs baseline: 1.1634x; 1.1634x over previous
//
#include <hip/hip_runtime.h>
#include <math.h>

#define H_    8
#define DK_   32
#define NT_   6
#define ET_   3
#define DIM_  256
#define LN_EPS 1e-5f
#define NMATS (NT_ * 7)   // per node type: Q, Kt[0..2], Vt[0..2]
#define NBLK  2048        // grid-stride blocks for edge score pass
#define NBIN  (ET_ * H_)  // 24
#define NSTEP 56          // 7 matrices x 8 K-slabs
#define TROWS 128         // rows per projection tile
#define MAXNB 1024        // max 256-thread blocks over n
#define ESB   1024        // blocks for hist+count fused kernel
#define PACKN (NMATS * 8 * 16 * 64)
#define BIASN (NMATS * 256)

typedef __attribute__((ext_vector_type(8))) short short8v;
typedef __attribute__((ext_vector_type(4))) float f32x4;
typedef __attribute__((ext_vector_type(2))) float f32x2;

__device__ __forceinline__ unsigned short f2bf(float f){
    unsigned u = __float_as_uint(f);
    return (unsigned short)((u + 0x7fffu + ((u >> 16) & 1u)) >> 16);
}
__device__ __forceinline__ float bflo(unsigned u){ return __uint_as_float(u << 16); }
__device__ __forceinline__ float bfhi(unsigned u){ return __uint_as_float(u & 0xFFFF0000u); }
__device__ __forceinline__ float bf2f(unsigned short v){ return __uint_as_float((unsigned)v << 16); }

// fp8 e4m3 via HW converter (self-consistent encode/decode on gfx950)
__device__ __forceinline__ unsigned char f2fp8(float f){
    int r = __builtin_amdgcn_cvt_pk_fp8_f32(f, f, 0, false);
    return (unsigned char)(r & 0xFF);
}

// ---------------- node hist + edge target count (fused) ----------------
__global__ __launch_bounds__(256) void k_histcount(
    const int* __restrict__ ntyp, int n, int* __restrict__ bhist, int nb,
    const int* __restrict__ ei, int E_, int* __restrict__ ecnt)
{
    const int tid = threadIdx.x;
    if ((int)blockIdx.x < nb){
        const int gi = blockIdx.x * 256 + tid;
        const int wave = tid >> 6, lane = tid & 63;
        const int t = (gi < n) ? ntyp[gi] : -1;
        __shared__ int whist[4][8];
        #pragma unroll
        for (int tt = 0; tt < NT_; tt++){
            unsigned long long bal = __ballot(t == tt);
            if (lane == 0) whist[wave][tt] = __popcll(bal);
        }
        __syncthreads();
        if (tid < NT_)
            bhist[blockIdx.x * 8 + tid] =
                whist[0][tid] + whist[1][tid] + whist[2][tid] + whist[3][tid];
    }
    for (int e = blockIdx.x * 256 + tid; e < E_; e += ESB * 256)
        atomicAdd(&ecnt[ei[E_ + e]], 1);
}

// single block; ALL dependent chains run against LDS, never global.
__global__ __launch_bounds__(256) void k_scanhist(int* __restrict__ bhist, int nb,
                                                  int* __restrict__ offs, int* __restrict__ meta){
    __shared__ int hh[MAXNB * 8 / 4];
    __shared__ int tot[8], toff[8], tbase[8], ntl_s;
    const int tid = threadIdx.x;

    for (int i = tid; i < nb * 8; i += 256) hh[i] = bhist[i];
    __syncthreads();

    if (tid < 8){
        int run = 0;
        for (int b = 0; b < nb; b++){
            int c = hh[b * 8 + tid];
            hh[b * 8 + tid] = run;
            run += c;
        }
        tot[tid] = run;
    }
    __syncthreads();

    if (tid == 0){
        int off = 0, tb = 0;
        for (int tt = 0; tt < NT_; tt++){
            toff[tt] = off;
            tbase[tt] = tb;
            tb += (tot[tt] + TROWS - 1) / TROWS;
            off += tot[tt];
        }
        for (int tt = NT_; tt < 8; tt++){ toff[tt] = 0; tbase[tt] = tb; }
        ntl_s = tb;
        meta[0] = tb;
    }
    __syncthreads();

    for (int i = tid; i < ntl_s; i += 256){
        int t = 0;
        #pragma unroll
        for (int tt = 1; tt < NT_; tt++) if (i >= tbase[tt]) t = tt;
        const int k = i - tbase[t];
        const int rem = tot[t] - k * TROWS;
        meta[1 + 3*i]     = t;
        meta[1 + 3*i + 1] = toff[t] + k * TROWS;
        meta[1 + 3*i + 2] = (rem < TROWS) ? rem : TROWS;
    }
    if (tid < NT_) offs[tid] = toff[tid];

    for (int i = tid; i < nb * 8; i += 256)
        bhist[i] = hh[i] + toff[i & 7];
}

// node rank-scatter + edge-count block scan (fused)
__global__ __launch_bounds__(256) void k_scatscan(
    const int* __restrict__ ntyp, int n, const int* __restrict__ bhist,
    int* __restrict__ sorted,
    const int* __restrict__ ecnt, int* __restrict__ eoff, int* __restrict__ bsum)
{
    const int tid = threadIdx.x;
    const int gi = blockIdx.x * 256 + tid;
    const int wave = tid >> 6, lane = tid & 63;
    const int t = (gi < n) ? ntyp[gi] : -1;
    __shared__ int whist[4][8];
    unsigned long long mybal = 0;
    #pragma unroll
    for (int tt = 0; tt < NT_; tt++){
        unsigned long long bal = __ballot(t == tt);
        if (lane == 0) whist[wave][tt] = __popcll(bal);
        if (t == tt) mybal = bal;
    }
    __syncthreads();
    if (gi < n){
        int wo = 0;
        for (int w = 0; w < wave; w++) wo += whist[w][t];
        const unsigned long long below = (lane == 0) ? 0ULL : (~0ULL >> (64 - lane));
        const int rank = bhist[blockIdx.x * 8 + t] + wo + __popcll(mybal & below);
        sorted[rank] = gi;
    }
    __shared__ int sh[256];
    int v = (gi < n) ? ecnt[gi] : 0;
    __syncthreads();
    sh[tid] = v;
    __syncthreads();
    for (int off = 1; off < 256; off <<= 1){
        int tv = (tid >= off) ? sh[tid - off] : 0;
        __syncthreads();
        sh[tid] += tv;
        __syncthreads();
    }
    if (gi < n) eoff[gi] = sh[tid] - v;
    if (tid == 255) bsum[blockIdx.x] = sh[255];
}

// ---------------- weight fuse + MFMA-fragment pack + bias (fused) ----------------
__global__ __launch_bounds__(256) void k_packbias(
    const float* __restrict__ Wq, const float* __restrict__ Wk, const float* __restrict__ Wv,
    const float* __restrict__ Wa, const float* __restrict__ Wm, const float* __restrict__ pri,
    const float* __restrict__ bq, const float* __restrict__ bk, const float* __restrict__ bv,
    unsigned short* __restrict__ pw, float* __restrict__ bpack)
{
    const int gid0 = blockIdx.x * 256 + threadIdx.x;
    if (gid0 < PACKN){
        const int gid = gid0;
        const int l = gid & 63;
        const int j = (gid >> 6) & 15;
        const int p = (gid >> 10) & 7;
        const int matg = gid >> 13;
        const int tn = matg / 7, m = matg % 7;
        const int col = j * 16 + (l & 15);
        const int k0  = p * 32 + (l >> 4) * 8;
        const int h = col >> 5, c = col & 31;

        float vals[8];
        if (m == 0){
            #pragma unroll
            for (int i = 0; i < 8; i++)
                vals[i] = Wq[((size_t)tn * 256 + (k0 + i)) * 256 + col];
        } else if (m <= 3){
            const int te = m - 1;
            const float scale = 0.17677669529663687f * pri[te * H_ + h];
            #pragma unroll
            for (int i = 0; i < 8; i++){
                const float* wk = Wk + ((size_t)tn * 256 + (k0 + i)) * 256 + h * 32;
                const float* wa = Wa + (size_t)te * 1024 + c;
                float s = 0.f;
                for (int d = 0; d < 32; d++) s = fmaf(wk[d], wa[d * 32], s);
                vals[i] = s * scale;
            }
        } else {
            const int te = m - 4;
            #pragma unroll
            for (int i = 0; i < 8; i++){
                const float* wv = Wv + ((size_t)tn * 256 + (k0 + i)) * 256 + h * 32;
                const float* wm = Wm + (size_t)te * 1024 + c;
                float s = 0.f;
                for (int d = 0; d < 32; d++) s = fmaf(wv[d], wm[d * 32], s);
                vals[i] = s;
            }
        }
        unsigned short o[8];
        #pragma unroll
        for (int i = 0; i < 8; i++) o[i] = f2bf(vals[i]);
        *reinterpret_cast<uint4*>(pw + (size_t)gid * 8) = *reinterpret_cast<const uint4*>(o);
    } else if (gid0 < PACKN + BIASN){
        const int gid = gid0 - PACKN;
        const int col = gid & 255;
        const int matg = gid >> 8;
        const int tn = matg / 7, m = matg % 7;
        const int h = col >> 5, c = col & 31;
        float v;
        if (m == 0) v = bq[tn * 256 + col];
        else if (m <= 3){
            const int te = m - 1;
            float s = 0.f;
            for (int d = 0; d < 32; d++) s = fmaf(bk[tn * 256 + h * 32 + d], Wa[te * 1024 + d * 32 + c], s);
            v = s * 0.17677669529663687f * pri[te * H_ + h];
        } else {
            const int te = m - 4;
            float s = 0.f;
            for (int d = 0; d < 32; d++) s = fmaf(bv[tn * 256 + h * 32 + d], Wm[te * 1024 + d * 32 + c], s);
            v = s;
        }
        bpack[gid] = v;
    }
}

// ---------------- MFMA grouped projection (7 matrices; Q->bf16, Kt/Vt->fp8) ----------------
__global__ __launch_bounds__(512, 2) void k_proj(
    const float* __restrict__ x, const int* __restrict__ sorted, const int* __restrict__ meta,
    const unsigned short* __restrict__ pw, const float* __restrict__ bpack,
    unsigned short* __restrict__ Qb, unsigned char* __restrict__ Ktb, unsigned char* __restrict__ Vtb)
{
    const int ntl = meta[0];
    if ((int)blockIdx.x >= ntl) return;
    const int q = ntl >> 3, r = ntl & 7;
    const int xcd = blockIdx.x & 7, ii = blockIdx.x >> 3;
    const int tile = (xcd < r) ? xcd * (q + 1) + ii
                               : r * (q + 1) + (xcd - r) * q + ii;
    const int tn    = meta[1 + 3*tile];
    const int start = meta[1 + 3*tile + 1];
    const int rows  = meta[1 + 3*tile + 2];

    __shared__ unsigned short xs[TROWS * 256];
    __shared__ int ids[TROWS];
    const int tid = threadIdx.x;
    if (tid < TROWS) ids[tid] = sorted[start + ((tid < rows) ? tid : 0)];
    __syncthreads();

    char* xb = reinterpret_cast<char*>(xs);
    for (int idx = tid; idx < TROWS * 32; idx += 512){
        const int r2 = idx >> 5, c16 = idx & 31;
        const float* src = x + (size_t)ids[r2] * DIM_ + c16 * 8;
        float4 a = *reinterpret_cast<const float4*>(src);
        float4 b = *reinterpret_cast<const float4*>(src + 4);
        unsigned short o[8] = {f2bf(a.x), f2bf(a.y), f2bf(a.z), f2bf(a.w),
                               f2bf(b.x), f2bf(b.y), f2bf(b.z), f2bf(b.w)};
        const int byte = r2 * 512 + ((c16 * 16) ^ ((r2 & 7) << 4));
        *reinterpret_cast<uint4*>(xb + byte) = *reinterpret_cast<const uint4*>(o);
    }
    __syncthreads();   // xs read-only from here on; NO barriers in the main loop

    const int wid = tid >> 6, l = tid & 63;
    const int rg = wid >> 2;
    const int cg = wid & 3;
    const int l15 = l & 15, lg = l >> 4;
    const int xorv = (l15 & 7) << 4;
    const size_t matbase = (size_t)tn * 7;
    const int rowbase = rg * 64;

    f32x4 acc[4][4];
    short8v b0[4], b1[4];

    {
        const unsigned short* sp0 = pw + matbase * 8 * 8192;
        #pragma unroll
        for (int j = 0; j < 4; j++)
            b0[j] = *reinterpret_cast<const short8v*>(sp0 + (cg * 4 + j) * 512 + l * 8);
    }

    auto proj_step = [&](const int s, short8v (&cur)[4], short8v (&pf)[4]){
        const int m = s >> 3, p = s & 7;
        const int matg = (int)matbase + m;

        if (s + 1 < NSTEP){
            const unsigned short* sp = pw + (matbase * 8 + (s + 1)) * 8192;
            #pragma unroll
            for (int j = 0; j < 4; j++)
                pf[j] = *reinterpret_cast<const short8v*>(sp + (cg * 4 + j) * 512 + l * 8);
        }

        if (p == 0){
            #pragma unroll
            for (int j = 0; j < 4; j++){
                const float bj = bpack[matg * 256 + cg * 64 + j * 16 + l15];
                #pragma unroll
                for (int i = 0; i < 4; i++) acc[i][j] = (f32x4){bj, bj, bj, bj};
            }
        }

        {
            short8v a[4];
            const int kb = (p * 64 + (lg << 4)) ^ xorv;
            #pragma unroll
            for (int i = 0; i < 4; i++)
                a[i] = *reinterpret_cast<const short8v*>(xb + (rowbase + i * 16 + l15) * 512 + kb);
            #pragma unroll
            for (int i = 0; i < 4; i++)
                #pragma unroll
                for (int j = 0; j < 4; j++)
                    acc[i][j] = __builtin_amdgcn_mfma_f32_16x16x32_bf16(a[i], cur[j], acc[i][j], 0, 0, 0);
        }

        if (p == 7){
            #pragma unroll
            for (int i = 0; i < 4; i++){
                #pragma unroll
                for (int rr = 0; rr < 4; rr++){
                    const int row = rowbase + i * 16 + lg * 4 + rr;
                    if (row < rows){
                        const size_t node = (size_t)ids[row];
                        if (m == 0){
                            unsigned short* optr = Qb + node * 256 + cg * 64 + l15;
                            #pragma unroll
                            for (int j = 0; j < 4; j++) optr[j * 16] = f2bf(acc[i][j][rr]);
                        } else {
                            unsigned char* optr = ((m <= 3) ? Ktb + node * 768 + (size_t)(m - 1) * 256
                                                            : Vtb + node * 768 + (size_t)(m - 4) * 256)
                                                  + cg * 64 + l15;
                            #pragma unroll
                            for (int j = 0; j < 4; j++) optr[j * 16] = f2fp8(acc[i][j][rr]);
                        }
                    }
                }
            }
        }
    };

    for (int s = 0; s < NSTEP; s += 2){
        proj_step(s,     b0, b1);
        proj_step(s + 1, b1, b0);
    }
}

// ---------------- remaining CSR scans ----------------
__global__ __launch_bounds__(256) void k_scan2(int* __restrict__ bsum, int nb){
    __shared__ int sh[MAXNB];
    const int tid = threadIdx.x;
    for (int i = tid; i < nb; i += 256) sh[i] = bsum[i];
    __syncthreads();
    if (tid == 0){
        int run = 0;
        for (int b = 0; b < nb; b++){ int c = sh[b]; sh[b] = run; run += c; }
    }
    __syncthreads();
    for (int i = tid; i < nb; i += 256) bsum[i] = sh[i];
}

__global__ __launch_bounds__(256) void k_scan3(int n, int E_, const int* __restrict__ bsum,
                                               int* __restrict__ eoff, int* __restrict__ cursor){
    const int gi = blockIdx.x * 256 + threadIdx.x;
    if (gi < n){
        int v = eoff[gi] + bsum[blockIdx.x];
        eoff[gi] = v;
        cursor[gi] = v;
    }
    if (gi == 0) eoff[n] = E_;
}

__global__ void k_escatter(const int* __restrict__ ei, const int* __restrict__ etyp, int E_,
                           int* __restrict__ cursor, int2* __restrict__ ep){
    int e = blockIdx.x * blockDim.x + threadIdx.x;
    if (e < E_){
        int tg = ei[E_ + e];
        int pos = atomicAdd(&cursor[tg], 1);
        ep[pos] = make_int2(ei[e] | (etyp[e] << 28), tg);
    }
}

// ---------------- scores: fp8-Kt gather x bf16 Q -> exp (bf16 SC) + per-(type,head) sum ----------------
__global__ __launch_bounds__(256) void k_score(
    const unsigned char* __restrict__ Ktb, const unsigned short* __restrict__ Qb,
    const int2* __restrict__ ep,
    unsigned short* __restrict__ SC, float* __restrict__ psum, int EH)
{
    const int tid = threadIdx.x;
    float s0 = 0.f, s1 = 0.f, s2 = 0.f;

    for (int idx = blockIdx.x * 256 + tid; idx < EH; idx += NBLK * 256){
        const int pos = idx >> 3, h = idx & 7;
        const int2 pr = ep[pos];
        const int s = pr.x & 0x0FFFFFFF, t = pr.x >> 28;
        const int tg = pr.y;
        const unsigned char*  kp = Ktb + ((size_t)s * 3 + t) * 256 + h * 32;  // 32 fp8
        const unsigned short* qp = Qb + (size_t)tg * 256 + h * 32;            // 32 bf16
        uint4 k8a = *reinterpret_cast<const uint4*>(kp);
        uint4 k8b = *reinterpret_cast<const uint4*>(kp + 16);
        unsigned kw[8] = {k8a.x, k8a.y, k8a.z, k8a.w, k8b.x, k8b.y, k8b.z, k8b.w};
        uint4 qa = *reinterpret_cast<const uint4*>(qp);
        uint4 qb = *reinterpret_cast<const uint4*>(qp + 8);
        uint4 qc = *reinterpret_cast<const uint4*>(qp + 16);
        uint4 qd = *reinterpret_cast<const uint4*>(qp + 24);
        unsigned qw[16] = {qa.x, qa.y, qa.z, qa.w, qb.x, qb.y, qb.z, qb.w,
                           qc.x, qc.y, qc.z, qc.w, qd.x, qd.y, qd.z, qd.w};
        float acc = 0.f;
        #pragma unroll
        for (int w = 0; w < 8; w++){
            f32x2 lo = __builtin_amdgcn_cvt_pk_f32_fp8(kw[w], false);
            f32x2 hi = __builtin_amdgcn_cvt_pk_f32_fp8(kw[w], true);
            acc = fmaf(lo.x, bflo(qw[2*w]),   acc);
            acc = fmaf(lo.y, bfhi(qw[2*w]),   acc);
            acc = fmaf(hi.x, bflo(qw[2*w+1]), acc);
            acc = fmaf(hi.y, bfhi(qw[2*w+1]), acc);
        }
        const float e = __expf(acc);
        SC[idx] = f2bf(e);
        s0 += (t == 0) ? e : 0.f;
        s1 += (t == 1) ? e : 0.f;
        s2 += (t == 2) ? e : 0.f;
    }

    #pragma unroll
    for (int s = 8; s <= 32; s <<= 1){
        s0 += __shfl_xor(s0, s, 64);
        s1 += __shfl_xor(s1, s, 64);
        s2 += __shfl_xor(s2, s, 64);
    }
    __shared__ float sm[4][NBIN];
    const int wave = tid >> 6, lane = tid & 63;
    if (lane < 8){ sm[wave][lane] = s0; sm[wave][8 + lane] = s1; sm[wave][16 + lane] = s2; }
    __syncthreads();
    if (tid < NBIN)
        psum[blockIdx.x * NBIN + tid] = sm[0][tid] + sm[1][tid] + sm[2][tid] + sm[3][tid];
}

__global__ __launch_bounds__(256) void k_redsum(const float* __restrict__ psum,
                                                float* __restrict__ rw){
    const int b = blockIdx.x, tid = threadIdx.x;
    float s = 0.f;
    for (int i = tid; i < NBLK; i += 256) s += psum[i * NBIN + b];
    #pragma unroll
    for (int m = 1; m < 64; m <<= 1) s += __shfl_xor(s, m, 64);
    __shared__ float sm[4];
    if ((tid & 63) == 0) sm[tid >> 6] = s;
    __syncthreads();
    if (tid == 0){
        float t = sm[0] + sm[1] + sm[2] + sm[3];
        rw[b] = (t > 0.f) ? 1.f / t : 0.f;
    }
}

// ---------------- gather aggregation (fp8 Vt, thread per (tg,h)) + skip + LN ----------------
__global__ __launch_bounds__(256) void k_aggln(
    const unsigned char* __restrict__ Vtb, const float* __restrict__ x,
    const int* __restrict__ eoff, const int2* __restrict__ ep,
    const unsigned short* __restrict__ SC, const float* __restrict__ rw,
    const float* __restrict__ g, const float* __restrict__ b,
    float* __restrict__ out, int n)
{
    const int idx = blockIdx.x * 256 + threadIdx.x;
    if (idx >= n * H_) return;
    const int tg = idx >> 3, h = idx & 7;

    const float rw0 = rw[h], rw1 = rw[8 + h], rw2 = rw[16 + h];

    float acc[DK_];
    #pragma unroll
    for (int k = 0; k < DK_; k++) acc[k] = 0.f;

    const int p1 = eoff[tg + 1];
    for (int pos = eoff[tg]; pos < p1; ++pos){
        const int pl = ep[pos].x;
        const int s = pl & 0x0FFFFFFF, t = pl >> 28;
        const float rwv = (t == 0) ? rw0 : (t == 1) ? rw1 : rw2;
        const float w = bf2f(SC[(size_t)pos * 8 + h]) * rwv;
        const unsigned char* vp = Vtb + ((size_t)s * 3 + t) * 256 + h * 32;  // 32 fp8
        uint4 v8a = *reinterpret_cast<const uint4*>(vp);
        uint4 v8b = *reinterpret_cast<const uint4*>(vp + 16);
        unsigned vw[8] = {v8a.x, v8a.y, v8a.z, v8a.w, v8b.x, v8b.y, v8b.z, v8b.w};
        #pragma unroll
        for (int q = 0; q < 8; q++){
            f32x2 lo = __builtin_amdgcn_cvt_pk_f32_fp8(vw[q], false);
            f32x2 hi = __builtin_amdgcn_cvt_pk_f32_fp8(vw[q], true);
            acc[4*q+0] = fmaf(w, lo.x, acc[4*q+0]);
            acc[4*q+1] = fmaf(w, lo.y, acc[4*q+1]);
            acc[4*q+2] = fmaf(w, hi.x, acc[4*q+2]);
            acc[4*q+3] = fmaf(w, hi.y, acc[4*q+3]);
        }
    }

    #pragma unroll
    for (int k4 = 0; k4 < 8; k4++){
        float4 x4 = *reinterpret_cast<const float4*>(x + (size_t)tg * DIM_ + h * DK_ + k4 * 4);
        acc[4*k4] += x4.x; acc[4*k4+1] += x4.y; acc[4*k4+2] += x4.z; acc[4*k4+3] += x4.w;
    }

    float s1 = 0.f, s2 = 0.f;
    #pragma unroll
    for (int k = 0; k < DK_; k++){ s1 += acc[k]; s2 = fmaf(acc[k], acc[k], s2); }
    #pragma unroll
    for (int m = 1; m <= 4; m <<= 1){
        s1 += __shfl_xor(s1, m, 64);
        s2 += __shfl_xor(s2, m, 64);
    }
    const float mu  = s1 * (1.f / DIM_);
    const float var = s2 * (1.f / DIM_) - mu * mu;
    const float rs  = rsqrtf(var + LN_EPS);

    float* __restrict__ o = out + (size_t)tg * DIM_ + h * DK_;
    #pragma unroll
    for (int k4 = 0; k4 < 8; k4++){
        float4 g4 = *reinterpret_cast<const float4*>(g + h * DK_ + k4 * 4);
        float4 b4 = *reinterpret_cast<const float4*>(b + h * DK_ + k4 * 4);
        float4 o4;
        o4.x = (acc[4*k4]   - mu) * rs * g4.x + b4.x;
        o4.y = (acc[4*k4+1] - mu) * rs * g4.y + b4.y;
        o4.z = (acc[4*k4+2] - mu) * rs * g4.z + b4.z;
        o4.w = (acc[4*k4+3] - mu) * rs * g4.w + b4.w;
        *reinterpret_cast<float4*>(o + k4 * 4) = o4;
    }
}

extern "C" void kernel_launch(void* const* d_in, const int* in_sizes, int n_in,
                              void* d_out, int out_size, void* d_ws, size_t ws_size,
                              hipStream_t stream)
{
    const float* x   = (const float*)d_in[0];
    const int*  ei   = (const int*)d_in[1];
    const int*  ntyp = (const int*)d_in[3];
    const int*  etyp = (const int*)d_in[4];
    const float* Wk  = (const float*)d_in[5];
    const float* bk  = (const float*)d_in[6];
    const float* Wq  = (const float*)d_in[7];
    const float* bq  = (const float*)d_in[8];
    const float* Wv  = (const float*)d_in[9];
    const float* bv  = (const float*)d_in[10];
    const float* pri = (const float*)d_in[11];
    const float* Wa  = (const float*)d_in[12];
    const float* Wm  = (const float*)d_in[13];
    const float* lg  = (const float*)d_in[14];
    const float* lb  = (const float*)d_in[15];

    const int n  = in_sizes[0] / DIM_;
    const int E_ = in_sizes[4];
    const int EH = E_ * H_;
    float* out = (float*)d_out;

    // ---- workspace layout ----
    const size_t NF = (size_t)n * DIM_;
    unsigned short* Qb  = (unsigned short*)d_ws;          // n*256 bf16 (raw Q)
    unsigned char*  Ktb = (unsigned char*)(Qb + NF);      // n*3*256 fp8 (K @ Wa[t], scaled)
    unsigned char*  Vtb = Ktb + NF * 3;                   // n*3*256 fp8 (V @ Wm[t])
    unsigned short* pwp = (unsigned short*)(Vtb + NF * 3);// NMATS*65536 bf16
    unsigned short* SC  = pwp + (size_t)NMATS * 65536;    // E*8 bf16 (CSR order, exp'd)
    float* bpack = (float*)(SC + (size_t)EH);             // NMATS*256
    float* psum  = bpack + NMATS * 256;                   // NBLK*24
    float* rw    = psum + (size_t)NBLK * NBIN;            // 24
    int* sorted  = (int*)(rw + NBIN);                     // n
    int* offsN   = sorted + n;                            // 8
    const int NB = (n + 255) / 256;
    int* bhist   = offsN + 8;                             // NB*8
    int* meta    = bhist + (size_t)NB * 8;                // 1 + 3*maxtiles
    const int maxtiles = (n + TROWS - 1) / TROWS + NT_;
    int* ecnt    = meta + 1 + 3 * maxtiles;               // n
    int* eoff    = ecnt + n;                              // n + 1
    int* cursorE = eoff + n + 1;                          // n
    int* bsum    = cursorE + n;                           // <= 1024
    int2* ep     = (int2*)(bsum + 1024);                  // E (payload, tgt)

    hipMemsetAsync(ecnt, 0, (size_t)n * sizeof(int), stream);

    // weight fuse/pack + bias (fused)
    k_packbias<<<(PACKN + BIASN + 255) / 256, 256, 0, stream>>>(
        Wq, Wk, Wv, Wa, Wm, pri, bq, bk, bv, pwp, bpack);

    // node hist + edge count (fused) -> scans -> scatter
    k_histcount<<<ESB, 256, 0, stream>>>(ntyp, n, bhist, NB, ei, E_, ecnt);
    k_scanhist <<<1, 256, 0, stream>>>(bhist, NB, offsN, meta);
    k_scatscan <<<NB, 256, 0, stream>>>(ntyp, n, bhist, sorted, ecnt, eoff, bsum);
    k_scan2    <<<1, 256, 0, stream>>>(bsum, NB);
    k_scan3    <<<NB, 256, 0, stream>>>(n, E_, bsum, eoff, cursorE);

    // fused MFMA projections
    k_proj<<<maxtiles, 512, 0, stream>>>(x, sorted, meta, pwp, bpack, Qb, Ktb, Vtb);

    // edge scatter -> CSR-ordered scores -> denominators -> gather-aggregate + LN
    k_escatter<<<(E_ + 255) / 256, 256, 0, stream>>>(ei, etyp, E_, cursorE, ep);
    k_score   <<<NBLK, 256, 0, stream>>>(Ktb, Qb, ep, SC, psum, EH);
    k_redsum  <<<NBIN, 256, 0, stream>>>(psum, rw);
    k_aggln   <<<(n * H_ + 255) / 256, 256, 0, stream>>>(Vtb, x, eoff, ep, SC, rw, lg, lb, out, n);
}

// Round 22
// 230.515 us; speedup vs baseline: 1.2103x; 1.0403x over previous
//
#include <hip/hip_runtime.h>
#include <math.h>

#define H_    8
#define DK_   32
#define NT_   6
#define ET_   3
#define DIM_  256
#define LN_EPS 1e-5f
#define NMATS (NT_ * 7)   // per node type: Q, Kt[0..2], Vt[0..2]
#define NBLK  2048        // grid-stride blocks for edge score pass
#define NBIN  (ET_ * H_)  // 24
#define NSTEP 56          // 7 matrices x 8 K-slabs
#define TROWS 128         // rows per projection tile
#define MAXNB 1024        // max 256-thread blocks over n
#define ESB   1024        // blocks for hist+count fused kernel
#define PACKN (NMATS * 8 * 16 * 64)
#define BIASN (NMATS * 256)

typedef __attribute__((ext_vector_type(8))) short short8v;
typedef __attribute__((ext_vector_type(4))) float f32x4;
typedef __attribute__((ext_vector_type(2))) float f32x2;

__device__ __forceinline__ unsigned short f2bf(float f){
    unsigned u = __float_as_uint(f);
    return (unsigned short)((u + 0x7fffu + ((u >> 16) & 1u)) >> 16);
}
__device__ __forceinline__ float bflo(unsigned u){ return __uint_as_float(u << 16); }
__device__ __forceinline__ float bfhi(unsigned u){ return __uint_as_float(u & 0xFFFF0000u); }
__device__ __forceinline__ float bf2f(unsigned short v){ return __uint_as_float((unsigned)v << 16); }

// fp8 e4m3 via HW converter (self-consistent encode/decode on gfx950)
__device__ __forceinline__ unsigned char f2fp8(float f){
    int r = __builtin_amdgcn_cvt_pk_fp8_f32(f, f, 0, false);
    return (unsigned char)(r & 0xFF);
}

// ---------------- node hist + edge target count (fused) ----------------
__global__ __launch_bounds__(256) void k_histcount(
    const int* __restrict__ ntyp, int n, int* __restrict__ bhist, int nb,
    const int* __restrict__ ei, int E_, int* __restrict__ ecnt)
{
    const int tid = threadIdx.x;
    if ((int)blockIdx.x < nb){
        const int gi = blockIdx.x * 256 + tid;
        const int wave = tid >> 6, lane = tid & 63;
        const int t = (gi < n) ? ntyp[gi] : -1;
        __shared__ int whist[4][8];
        #pragma unroll
        for (int tt = 0; tt < NT_; tt++){
            unsigned long long bal = __ballot(t == tt);
            if (lane == 0) whist[wave][tt] = __popcll(bal);
        }
        __syncthreads();
        if (tid < NT_)
            bhist[blockIdx.x * 8 + tid] =
                whist[0][tid] + whist[1][tid] + whist[2][tid] + whist[3][tid];
    }
    for (int e = blockIdx.x * 256 + tid; e < E_; e += ESB * 256)
        atomicAdd(&ecnt[ei[E_ + e]], 1);
}

// single block; ALL dependent chains run against LDS, never global.
__global__ __launch_bounds__(256) void k_scanhist(int* __restrict__ bhist, int nb,
                                                  int* __restrict__ offs, int* __restrict__ meta){
    __shared__ int hh[MAXNB * 8 / 4];
    __shared__ int tot[8], toff[8], tbase[8], ntl_s;
    const int tid = threadIdx.x;

    for (int i = tid; i < nb * 8; i += 256) hh[i] = bhist[i];
    __syncthreads();

    if (tid < 8){
        int run = 0;
        for (int b = 0; b < nb; b++){
            int c = hh[b * 8 + tid];
            hh[b * 8 + tid] = run;
            run += c;
        }
        tot[tid] = run;
    }
    __syncthreads();

    if (tid == 0){
        int off = 0, tb = 0;
        for (int tt = 0; tt < NT_; tt++){
            toff[tt] = off;
            tbase[tt] = tb;
            tb += (tot[tt] + TROWS - 1) / TROWS;
            off += tot[tt];
        }
        for (int tt = NT_; tt < 8; tt++){ toff[tt] = 0; tbase[tt] = tb; }
        ntl_s = tb;
        meta[0] = tb;
    }
    __syncthreads();

    for (int i = tid; i < ntl_s; i += 256){
        int t = 0;
        #pragma unroll
        for (int tt = 1; tt < NT_; tt++) if (i >= tbase[tt]) t = tt;
        const int k = i - tbase[t];
        const int rem = tot[t] - k * TROWS;
        meta[1 + 3*i]     = t;
        meta[1 + 3*i + 1] = toff[t] + k * TROWS;
        meta[1 + 3*i + 2] = (rem < TROWS) ? rem : TROWS;
    }
    if (tid < NT_) offs[tid] = toff[tid];

    for (int i = tid; i < nb * 8; i += 256)
        bhist[i] = hh[i] + toff[i & 7];
}

// node rank-scatter + edge-count block scan (fused)
__global__ __launch_bounds__(256) void k_scatscan(
    const int* __restrict__ ntyp, int n, const int* __restrict__ bhist,
    int* __restrict__ sorted,
    const int* __restrict__ ecnt, int* __restrict__ eoff, int* __restrict__ bsum)
{
    const int tid = threadIdx.x;
    const int gi = blockIdx.x * 256 + tid;
    const int wave = tid >> 6, lane = tid & 63;
    const int t = (gi < n) ? ntyp[gi] : -1;
    __shared__ int whist[4][8];
    unsigned long long mybal = 0;
    #pragma unroll
    for (int tt = 0; tt < NT_; tt++){
        unsigned long long bal = __ballot(t == tt);
        if (lane == 0) whist[wave][tt] = __popcll(bal);
        if (t == tt) mybal = bal;
    }
    __syncthreads();
    if (gi < n){
        int wo = 0;
        for (int w = 0; w < wave; w++) wo += whist[w][t];
        const unsigned long long below = (lane == 0) ? 0ULL : (~0ULL >> (64 - lane));
        const int rank = bhist[blockIdx.x * 8 + t] + wo + __popcll(mybal & below);
        sorted[rank] = gi;
    }
    __shared__ int sh[256];
    int v = (gi < n) ? ecnt[gi] : 0;
    __syncthreads();
    sh[tid] = v;
    __syncthreads();
    for (int off = 1; off < 256; off <<= 1){
        int tv = (tid >= off) ? sh[tid - off] : 0;
        __syncthreads();
        sh[tid] += tv;
        __syncthreads();
    }
    if (gi < n) eoff[gi] = sh[tid] - v;
    if (tid == 255) bsum[blockIdx.x] = sh[255];
}

// ---------------- weight fuse + MFMA-fragment pack + bias (fused) ----------------
__global__ __launch_bounds__(256) void k_packbias(
    const float* __restrict__ Wq, const float* __restrict__ Wk, const float* __restrict__ Wv,
    const float* __restrict__ Wa, const float* __restrict__ Wm, const float* __restrict__ pri,
    const float* __restrict__ bq, const float* __restrict__ bk, const float* __restrict__ bv,
    unsigned short* __restrict__ pw, float* __restrict__ bpack)
{
    const int gid0 = blockIdx.x * 256 + threadIdx.x;
    if (gid0 < PACKN){
        const int gid = gid0;
        const int l = gid & 63;
        const int j = (gid >> 6) & 15;
        const int p = (gid >> 10) & 7;
        const int matg = gid >> 13;
        const int tn = matg / 7, m = matg % 7;
        const int col = j * 16 + (l & 15);
        const int k0  = p * 32 + (l >> 4) * 8;
        const int h = col >> 5, c = col & 31;

        float vals[8];
        if (m == 0){
            #pragma unroll
            for (int i = 0; i < 8; i++)
                vals[i] = Wq[((size_t)tn * 256 + (k0 + i)) * 256 + col];
        } else if (m <= 3){
            const int te = m - 1;
            const float scale = 0.17677669529663687f * pri[te * H_ + h];
            #pragma unroll
            for (int i = 0; i < 8; i++){
                const float* wk = Wk + ((size_t)tn * 256 + (k0 + i)) * 256 + h * 32;
                const float* wa = Wa + (size_t)te * 1024 + c;
                float s = 0.f;
                for (int d = 0; d < 32; d++) s = fmaf(wk[d], wa[d * 32], s);
                vals[i] = s * scale;
            }
        } else {
            const int te = m - 4;
            #pragma unroll
            for (int i = 0; i < 8; i++){
                const float* wv = Wv + ((size_t)tn * 256 + (k0 + i)) * 256 + h * 32;
                const float* wm = Wm + (size_t)te * 1024 + c;
                float s = 0.f;
                for (int d = 0; d < 32; d++) s = fmaf(wv[d], wm[d * 32], s);
                vals[i] = s;
            }
        }
        unsigned short o[8];
        #pragma unroll
        for (int i = 0; i < 8; i++) o[i] = f2bf(vals[i]);
        *reinterpret_cast<uint4*>(pw + (size_t)gid * 8) = *reinterpret_cast<const uint4*>(o);
    } else if (gid0 < PACKN + BIASN){
        const int gid = gid0 - PACKN;
        const int col = gid & 255;
        const int matg = gid >> 8;
        const int tn = matg / 7, m = matg % 7;
        const int h = col >> 5, c = col & 31;
        float v;
        if (m == 0) v = bq[tn * 256 + col];
        else if (m <= 3){
            const int te = m - 1;
            float s = 0.f;
            for (int d = 0; d < 32; d++) s = fmaf(bk[tn * 256 + h * 32 + d], Wa[te * 1024 + d * 32 + c], s);
            v = s * 0.17677669529663687f * pri[te * H_ + h];
        } else {
            const int te = m - 4;
            float s = 0.f;
            for (int d = 0; d < 32; d++) s = fmaf(bv[tn * 256 + h * 32 + d], Wm[te * 1024 + d * 32 + c], s);
            v = s;
        }
        bpack[gid] = v;
    }
}

// ---------------- MFMA grouped projection (7 matrices; ALL outputs fp8) ----------------
__global__ __launch_bounds__(512, 2) void k_proj(
    const float* __restrict__ x, const int* __restrict__ sorted, const int* __restrict__ meta,
    const unsigned short* __restrict__ pw, const float* __restrict__ bpack,
    unsigned char* __restrict__ Qb, unsigned char* __restrict__ Ktb, unsigned char* __restrict__ Vtb)
{
    const int ntl = meta[0];
    if ((int)blockIdx.x >= ntl) return;
    const int q = ntl >> 3, r = ntl & 7;
    const int xcd = blockIdx.x & 7, ii = blockIdx.x >> 3;
    const int tile = (xcd < r) ? xcd * (q + 1) + ii
                               : r * (q + 1) + (xcd - r) * q + ii;
    const int tn    = meta[1 + 3*tile];
    const int start = meta[1 + 3*tile + 1];
    const int rows  = meta[1 + 3*tile + 2];

    __shared__ unsigned short xs[TROWS * 256];
    __shared__ int ids[TROWS];
    const int tid = threadIdx.x;
    if (tid < TROWS) ids[tid] = sorted[start + ((tid < rows) ? tid : 0)];
    __syncthreads();

    char* xb = reinterpret_cast<char*>(xs);
    for (int idx = tid; idx < TROWS * 32; idx += 512){
        const int r2 = idx >> 5, c16 = idx & 31;
        const float* src = x + (size_t)ids[r2] * DIM_ + c16 * 8;
        float4 a = *reinterpret_cast<const float4*>(src);
        float4 b = *reinterpret_cast<const float4*>(src + 4);
        unsigned short o[8] = {f2bf(a.x), f2bf(a.y), f2bf(a.z), f2bf(a.w),
                               f2bf(b.x), f2bf(b.y), f2bf(b.z), f2bf(b.w)};
        const int byte = r2 * 512 + ((c16 * 16) ^ ((r2 & 7) << 4));
        *reinterpret_cast<uint4*>(xb + byte) = *reinterpret_cast<const uint4*>(o);
    }
    __syncthreads();   // xs read-only from here on; NO barriers in the main loop

    const int wid = tid >> 6, l = tid & 63;
    const int rg = wid >> 2;
    const int cg = wid & 3;
    const int l15 = l & 15, lg = l >> 4;
    const int xorv = (l15 & 7) << 4;
    const size_t matbase = (size_t)tn * 7;
    const int rowbase = rg * 64;

    f32x4 acc[4][4];
    short8v b0[4], b1[4];

    {
        const unsigned short* sp0 = pw + matbase * 8 * 8192;
        #pragma unroll
        for (int j = 0; j < 4; j++)
            b0[j] = *reinterpret_cast<const short8v*>(sp0 + (cg * 4 + j) * 512 + l * 8);
    }

    auto proj_step = [&](const int s, short8v (&cur)[4], short8v (&pf)[4]){
        const int m = s >> 3, p = s & 7;
        const int matg = (int)matbase + m;

        if (s + 1 < NSTEP){
            const unsigned short* sp = pw + (matbase * 8 + (s + 1)) * 8192;
            #pragma unroll
            for (int j = 0; j < 4; j++)
                pf[j] = *reinterpret_cast<const short8v*>(sp + (cg * 4 + j) * 512 + l * 8);
        }

        if (p == 0){
            #pragma unroll
            for (int j = 0; j < 4; j++){
                const float bj = bpack[matg * 256 + cg * 64 + j * 16 + l15];
                #pragma unroll
                for (int i = 0; i < 4; i++) acc[i][j] = (f32x4){bj, bj, bj, bj};
            }
        }

        {
            short8v a[4];
            const int kb = (p * 64 + (lg << 4)) ^ xorv;
            #pragma unroll
            for (int i = 0; i < 4; i++)
                a[i] = *reinterpret_cast<const short8v*>(xb + (rowbase + i * 16 + l15) * 512 + kb);
            #pragma unroll
            for (int i = 0; i < 4; i++)
                #pragma unroll
                for (int j = 0; j < 4; j++)
                    acc[i][j] = __builtin_amdgcn_mfma_f32_16x16x32_bf16(a[i], cur[j], acc[i][j], 0, 0, 0);
        }

        if (p == 7){
            #pragma unroll
            for (int i = 0; i < 4; i++){
                #pragma unroll
                for (int rr = 0; rr < 4; rr++){
                    const int row = rowbase + i * 16 + lg * 4 + rr;
                    if (row < rows){
                        const size_t node = (size_t)ids[row];
                        unsigned char* optr;
                        if (m == 0)       optr = Qb  + node * 256;
                        else if (m <= 3)  optr = Ktb + node * 768 + (size_t)(m - 1) * 256;
                        else              optr = Vtb + node * 768 + (size_t)(m - 4) * 256;
                        optr += cg * 64 + l15;
                        #pragma unroll
                        for (int j = 0; j < 4; j++) optr[j * 16] = f2fp8(acc[i][j][rr]);
                    }
                }
            }
        }
    };

    for (int s = 0; s < NSTEP; s += 2){
        proj_step(s,     b0, b1);
        proj_step(s + 1, b1, b0);
    }
}

// ---------------- remaining CSR scans ----------------
__global__ __launch_bounds__(256) void k_scan2(int* __restrict__ bsum, int nb){
    __shared__ int sh[MAXNB];
    const int tid = threadIdx.x;
    for (int i = tid; i < nb; i += 256) sh[i] = bsum[i];
    __syncthreads();
    if (tid == 0){
        int run = 0;
        for (int b = 0; b < nb; b++){ int c = sh[b]; sh[b] = run; run += c; }
    }
    __syncthreads();
    for (int i = tid; i < nb; i += 256) bsum[i] = sh[i];
}

__global__ __launch_bounds__(256) void k_scan3(int n, int E_, const int* __restrict__ bsum,
                                               int* __restrict__ eoff, int* __restrict__ cursor){
    const int gi = blockIdx.x * 256 + threadIdx.x;
    if (gi < n){
        int v = eoff[gi] + bsum[blockIdx.x];
        eoff[gi] = v;
        cursor[gi] = v;
    }
    if (gi == 0) eoff[n] = E_;
}

__global__ void k_escatter(const int* __restrict__ ei, const int* __restrict__ etyp, int E_,
                           int* __restrict__ cursor, int2* __restrict__ ep){
    int e = blockIdx.x * blockDim.x + threadIdx.x;
    if (e < E_){
        int tg = ei[E_ + e];
        int pos = atomicAdd(&cursor[tg], 1);
        ep[pos] = make_int2(ei[e] | (etyp[e] << 28), tg);
    }
}

// ---------------- scores: fp8 Kt x fp8 Q -> exp (bf16 SC) + per-(type,head) sum ----------------
__global__ __launch_bounds__(256) void k_score(
    const unsigned char* __restrict__ Ktb, const unsigned char* __restrict__ Qb,
    const int2* __restrict__ ep,
    unsigned short* __restrict__ SC, float* __restrict__ psum, int EH)
{
    const int tid = threadIdx.x;
    float s0 = 0.f, s1 = 0.f, s2 = 0.f;

    for (int idx = blockIdx.x * 256 + tid; idx < EH; idx += NBLK * 256){
        const int pos = idx >> 3, h = idx & 7;
        const int2 pr = ep[pos];
        const int s = pr.x & 0x0FFFFFFF, t = pr.x >> 28;
        const int tg = pr.y;
        const unsigned char* kp = Ktb + ((size_t)s * 3 + t) * 256 + h * 32;   // 32 fp8
        const unsigned char* qp = Qb + (size_t)tg * 256 + h * 32;             // 32 fp8
        uint4 k8a = *reinterpret_cast<const uint4*>(kp);
        uint4 k8b = *reinterpret_cast<const uint4*>(kp + 16);
        unsigned kw[8] = {k8a.x, k8a.y, k8a.z, k8a.w, k8b.x, k8b.y, k8b.z, k8b.w};
        uint4 q8a = *reinterpret_cast<const uint4*>(qp);
        uint4 q8b = *reinterpret_cast<const uint4*>(qp + 16);
        unsigned qw[8] = {q8a.x, q8a.y, q8a.z, q8a.w, q8b.x, q8b.y, q8b.z, q8b.w};
        float acc = 0.f;
        #pragma unroll
        for (int w = 0; w < 8; w++){
            f32x2 klo = __builtin_amdgcn_cvt_pk_f32_fp8(kw[w], false);
            f32x2 khi = __builtin_amdgcn_cvt_pk_f32_fp8(kw[w], true);
            f32x2 qlo = __builtin_amdgcn_cvt_pk_f32_fp8(qw[w], false);
            f32x2 qhi = __builtin_amdgcn_cvt_pk_f32_fp8(qw[w], true);
            acc = fmaf(klo.x, qlo.x, acc);
            acc = fmaf(klo.y, qlo.y, acc);
            acc = fmaf(khi.x, qhi.x, acc);
            acc = fmaf(khi.y, qhi.y, acc);
        }
        const float e = __expf(acc);
        SC[idx] = f2bf(e);
        s0 += (t == 0) ? e : 0.f;
        s1 += (t == 1) ? e : 0.f;
        s2 += (t == 2) ? e : 0.f;
    }

    #pragma unroll
    for (int s = 8; s <= 32; s <<= 1){
        s0 += __shfl_xor(s0, s, 64);
        s1 += __shfl_xor(s1, s, 64);
        s2 += __shfl_xor(s2, s, 64);
    }
    __shared__ float sm[4][NBIN];
    const int wave = tid >> 6, lane = tid & 63;
    if (lane < 8){ sm[wave][lane] = s0; sm[wave][8 + lane] = s1; sm[wave][16 + lane] = s2; }
    __syncthreads();
    if (tid < NBIN)
        psum[blockIdx.x * NBIN + tid] = sm[0][tid] + sm[1][tid] + sm[2][tid] + sm[3][tid];
}

__global__ __launch_bounds__(256) void k_redsum(const float* __restrict__ psum,
                                                float* __restrict__ rw){
    const int b = blockIdx.x, tid = threadIdx.x;
    float s = 0.f;
    for (int i = tid; i < NBLK; i += 256) s += psum[i * NBIN + b];
    #pragma unroll
    for (int m = 1; m < 64; m <<= 1) s += __shfl_xor(s, m, 64);
    __shared__ float sm[4];
    if ((tid & 63) == 0) sm[tid >> 6] = s;
    __syncthreads();
    if (tid == 0){
        float t = sm[0] + sm[1] + sm[2] + sm[3];
        rw[b] = (t > 0.f) ? 1.f / t : 0.f;
    }
}

// ---------------- gather aggregation (fp8 Vt, thread per (tg,h)) + skip + LN ----------------
__global__ __launch_bounds__(256) void k_aggln(
    const unsigned char* __restrict__ Vtb, const float* __restrict__ x,
    const int* __restrict__ eoff, const int2* __restrict__ ep,
    const unsigned short* __restrict__ SC, const float* __restrict__ rw,
    const float* __restrict__ g, const float* __restrict__ b,
    float* __restrict__ out, int n)
{
    const int idx = blockIdx.x * 256 + threadIdx.x;
    if (idx >= n * H_) return;
    const int tg = idx >> 3, h = idx & 7;

    const float rw0 = rw[h], rw1 = rw[8 + h], rw2 = rw[16 + h];

    float acc[DK_];
    #pragma unroll
    for (int k = 0; k < DK_; k++) acc[k] = 0.f;

    const int p1 = eoff[tg + 1];
    for (int pos = eoff[tg]; pos < p1; ++pos){
        const int pl = ep[pos].x;
        const int s = pl & 0x0FFFFFFF, t = pl >> 28;
        const float rwv = (t == 0) ? rw0 : (t == 1) ? rw1 : rw2;
        const float w = bf2f(SC[(size_t)pos * 8 + h]) * rwv;
        const unsigned char* vp = Vtb + ((size_t)s * 3 + t) * 256 + h * 32;  // 32 fp8
        uint4 v8a = *reinterpret_cast<const uint4*>(vp);
        uint4 v8b = *reinterpret_cast<const uint4*>(vp + 16);
        unsigned vw[8] = {v8a.x, v8a.y, v8a.z, v8a.w, v8b.x, v8b.y, v8b.z, v8b.w};
        #pragma unroll
        for (int q = 0; q < 8; q++){
            f32x2 lo = __builtin_amdgcn_cvt_pk_f32_fp8(vw[q], false);
            f32x2 hi = __builtin_amdgcn_cvt_pk_f32_fp8(vw[q], true);
            acc[4*q+0] = fmaf(w, lo.x, acc[4*q+0]);
            acc[4*q+1] = fmaf(w, lo.y, acc[4*q+1]);
            acc[4*q+2] = fmaf(w, hi.x, acc[4*q+2]);
            acc[4*q+3] = fmaf(w, hi.y, acc[4*q+3]);
        }
    }

    #pragma unroll
    for (int k4 = 0; k4 < 8; k4++){
        float4 x4 = *reinterpret_cast<const float4*>(x + (size_t)tg * DIM_ + h * DK_ + k4 * 4);
        acc[4*k4] += x4.x; acc[4*k4+1] += x4.y; acc[4*k4+2] += x4.z; acc[4*k4+3] += x4.w;
    }

    float s1 = 0.f, s2 = 0.f;
    #pragma unroll
    for (int k = 0; k < DK_; k++){ s1 += acc[k]; s2 = fmaf(acc[k], acc[k], s2); }
    #pragma unroll
    for (int m = 1; m <= 4; m <<= 1){
        s1 += __shfl_xor(s1, m, 64);
        s2 += __shfl_xor(s2, m, 64);
    }
    const float mu  = s1 * (1.f / DIM_);
    const float var = s2 * (1.f / DIM_) - mu * mu;
    const float rs  = rsqrtf(var + LN_EPS);

    float* __restrict__ o = out + (size_t)tg * DIM_ + h * DK_;
    #pragma unroll
    for (int k4 = 0; k4 < 8; k4++){
        float4 g4 = *reinterpret_cast<const float4*>(g + h * DK_ + k4 * 4);
        float4 b4 = *reinterpret_cast<const float4*>(b + h * DK_ + k4 * 4);
        float4 o4;
        o4.x = (acc[4*k4]   - mu) * rs * g4.x + b4.x;
        o4.y = (acc[4*k4+1] - mu) * rs * g4.y + b4.y;
        o4.z = (acc[4*k4+2] - mu) * rs * g4.z + b4.z;
        o4.w = (acc[4*k4+3] - mu) * rs * g4.w + b4.w;
        *reinterpret_cast<float4*>(o + k4 * 4) = o4;
    }
}

extern "C" void kernel_launch(void* const* d_in, const int* in_sizes, int n_in,
                              void* d_out, int out_size, void* d_ws, size_t ws_size,
                              hipStream_t stream)
{
    const float* x   = (const float*)d_in[0];
    const int*  ei   = (const int*)d_in[1];
    const int*  ntyp = (const int*)d_in[3];
    const int*  etyp = (const int*)d_in[4];
    const float* Wk  = (const float*)d_in[5];
    const float* bk  = (const float*)d_in[6];
    const float* Wq  = (const float*)d_in[7];
    const float* bq  = (const float*)d_in[8];
    const float* Wv  = (const float*)d_in[9];
    const float* bv  = (const float*)d_in[10];
    const float* pri = (const float*)d_in[11];
    const float* Wa  = (const float*)d_in[12];
    const float* Wm  = (const float*)d_in[13];
    const float* lg  = (const float*)d_in[14];
    const float* lb  = (const float*)d_in[15];

    const int n  = in_sizes[0] / DIM_;
    const int E_ = in_sizes[4];
    const int EH = E_ * H_;
    float* out = (float*)d_out;

    // ---- workspace layout ----
    const size_t NF = (size_t)n * DIM_;
    unsigned char*  Qb  = (unsigned char*)d_ws;           // n*256 fp8 (raw Q)
    unsigned char*  Ktb = Qb + NF;                        // n*3*256 fp8 (K @ Wa[t], scaled)
    unsigned char*  Vtb = Ktb + NF * 3;                   // n*3*256 fp8 (V @ Wm[t])
    unsigned short* pwp = (unsigned short*)(Vtb + NF * 3);// NMATS*65536 bf16
    unsigned short* SC  = pwp + (size_t)NMATS * 65536;    // E*8 bf16 (CSR order, exp'd)
    float* bpack = (float*)(SC + (size_t)EH);             // NMATS*256
    float* psum  = bpack + NMATS * 256;                   // NBLK*24
    float* rw    = psum + (size_t)NBLK * NBIN;            // 24
    int* sorted  = (int*)(rw + NBIN);                     // n
    int* offsN   = sorted + n;                            // 8
    const int NB = (n + 255) / 256;
    int* bhist   = offsN + 8;                             // NB*8
    int* meta    = bhist + (size_t)NB * 8;                // 1 + 3*maxtiles
    const int maxtiles = (n + TROWS - 1) / TROWS + NT_;
    int* ecnt    = meta + 1 + 3 * maxtiles;               // n
    int* eoff    = ecnt + n;                              // n + 1
    int* cursorE = eoff + n + 1;                          // n
    int* bsum    = cursorE + n;                           // <= 1024
    int2* ep     = (int2*)(bsum + 1024);                  // E (payload, tgt)

    hipMemsetAsync(ecnt, 0, (size_t)n * sizeof(int), stream);

    // weight fuse/pack + bias (fused)
    k_packbias<<<(PACKN + BIASN + 255) / 256, 256, 0, stream>>>(
        Wq, Wk, Wv, Wa, Wm, pri, bq, bk, bv, pwp, bpack);

    // node hist + edge count (fused) -> scans -> scatter
    k_histcount<<<ESB, 256, 0, stream>>>(ntyp, n, bhist, NB, ei, E_, ecnt);
    k_scanhist <<<1, 256, 0, stream>>>(bhist, NB, offsN, meta);
    k_scatscan <<<NB, 256, 0, stream>>>(ntyp, n, bhist, sorted, ecnt, eoff, bsum);
    k_scan2    <<<1, 256, 0, stream>>>(bsum, NB);
    k_scan3    <<<NB, 256, 0, stream>>>(n, E_, bsum, eoff, cursorE);

    // fused MFMA projections
    k_proj<<<maxtiles, 512, 0, stream>>>(x, sorted, meta, pwp, bpack, Qb, Ktb, Vtb);

    // edge scatter -> CSR-ordered scores -> denominators -> gather-aggregate + LN
    k_escatter<<<(E_ + 255) / 256, 256, 0, stream>>>(ei, etyp, E_, cursorE, ep);
    k_score   <<<NBLK, 256, 0, stream>>>(Ktb, Qb, ep, SC, psum, EH);
    k_redsum  <<<NBIN, 256, 0, stream>>>(psum, rw);
    k_aggln   <<<(n * H_ + 255) / 256, 256, 0, stream>>>(Vtb, x, eoff, ep, SC, rw, lg, lb, out, n);
}

// Round 23
// 216.233 us; speedup vs baseline: 1.2903x; 1.0660x over previous
//
#include <hip/hip_runtime.h>
#include <math.h>

#define H_    8
#define DK_   32
#define NT_   6
#define ET_   3
#define DIM_  256
#define LN_EPS 1e-5f
#define NMATS (NT_ * 7)   // per node type: Q, Kt[0..2], Vt[0..2]
#define NBLK  2048        // grid-stride blocks for edge score pass
#define NBIN  (ET_ * H_)  // 24
#define NSTEP 56          // 7 matrices x 8 K-slabs
#define TROWS 128         // rows per projection tile
#define MAXNB 1024        // max 256-thread blocks over n
#define ESB   1024        // blocks for hist+count fused kernel
#define PACKN (NMATS * 8 * 16 * 64)
#define BIASN (NMATS * 256)

typedef __attribute__((ext_vector_type(8))) short short8v;
typedef __attribute__((ext_vector_type(4))) float f32x4;
typedef __attribute__((ext_vector_type(2))) float f32x2;

__device__ __forceinline__ unsigned short f2bf(float f){
    unsigned u = __float_as_uint(f);
    return (unsigned short)((u + 0x7fffu + ((u >> 16) & 1u)) >> 16);
}
__device__ __forceinline__ float bflo(unsigned u){ return __uint_as_float(u << 16); }
__device__ __forceinline__ float bfhi(unsigned u){ return __uint_as_float(u & 0xFFFF0000u); }
__device__ __forceinline__ float bf2f(unsigned short v){ return __uint_as_float((unsigned)v << 16); }

// fp8 e4m3 via HW converter (self-consistent encode/decode on gfx950)
__device__ __forceinline__ unsigned char f2fp8(float f){
    int r = __builtin_amdgcn_cvt_pk_fp8_f32(f, f, 0, false);
    return (unsigned char)(r & 0xFF);
}

// ---------------- node hist + edge target count (fused) ----------------
__global__ __launch_bounds__(256) void k_histcount(
    const int* __restrict__ ntyp, int n, int* __restrict__ bhist, int nb,
    const int* __restrict__ ei, int E_, int* __restrict__ ecnt)
{
    const int tid = threadIdx.x;
    if ((int)blockIdx.x < nb){
        const int gi = blockIdx.x * 256 + tid;
        const int wave = tid >> 6, lane = tid & 63;
        const int t = (gi < n) ? ntyp[gi] : -1;
        __shared__ int whist[4][8];
        #pragma unroll
        for (int tt = 0; tt < NT_; tt++){
            unsigned long long bal = __ballot(t == tt);
            if (lane == 0) whist[wave][tt] = __popcll(bal);
        }
        __syncthreads();
        if (tid < NT_)
            bhist[blockIdx.x * 8 + tid] =
                whist[0][tid] + whist[1][tid] + whist[2][tid] + whist[3][tid];
    }
    for (int e = blockIdx.x * 256 + tid; e < E_; e += ESB * 256)
        atomicAdd(&ecnt[ei[E_ + e]], 1);
}

// single block; ALL dependent chains run against LDS, never global.
__global__ __launch_bounds__(256) void k_scanhist(int* __restrict__ bhist, int nb,
                                                  int* __restrict__ offs, int* __restrict__ meta){
    __shared__ int hh[MAXNB * 8 / 4];
    __shared__ int tot[8], toff[8], tbase[8], ntl_s;
    const int tid = threadIdx.x;

    for (int i = tid; i < nb * 8; i += 256) hh[i] = bhist[i];
    __syncthreads();

    if (tid < 8){
        int run = 0;
        for (int b = 0; b < nb; b++){
            int c = hh[b * 8 + tid];
            hh[b * 8 + tid] = run;
            run += c;
        }
        tot[tid] = run;
    }
    __syncthreads();

    if (tid == 0){
        int off = 0, tb = 0;
        for (int tt = 0; tt < NT_; tt++){
            toff[tt] = off;
            tbase[tt] = tb;
            tb += (tot[tt] + TROWS - 1) / TROWS;
            off += tot[tt];
        }
        for (int tt = NT_; tt < 8; tt++){ toff[tt] = 0; tbase[tt] = tb; }
        ntl_s = tb;
        meta[0] = tb;
    }
    __syncthreads();

    for (int i = tid; i < ntl_s; i += 256){
        int t = 0;
        #pragma unroll
        for (int tt = 1; tt < NT_; tt++) if (i >= tbase[tt]) t = tt;
        const int k = i - tbase[t];
        const int rem = tot[t] - k * TROWS;
        meta[1 + 3*i]     = t;
        meta[1 + 3*i + 1] = toff[t] + k * TROWS;
        meta[1 + 3*i + 2] = (rem < TROWS) ? rem : TROWS;
    }
    if (tid < NT_) offs[tid] = toff[tid];

    for (int i = tid; i < nb * 8; i += 256)
        bhist[i] = hh[i] + toff[i & 7];
}

// node rank-scatter + edge-count block scan (fused)
__global__ __launch_bounds__(256) void k_scatscan(
    const int* __restrict__ ntyp, int n, const int* __restrict__ bhist,
    int* __restrict__ sorted,
    const int* __restrict__ ecnt, int* __restrict__ eoff, int* __restrict__ bsum)
{
    const int tid = threadIdx.x;
    const int gi = blockIdx.x * 256 + tid;
    const int wave = tid >> 6, lane = tid & 63;
    const int t = (gi < n) ? ntyp[gi] : -1;
    __shared__ int whist[4][8];
    unsigned long long mybal = 0;
    #pragma unroll
    for (int tt = 0; tt < NT_; tt++){
        unsigned long long bal = __ballot(t == tt);
        if (lane == 0) whist[wave][tt] = __popcll(bal);
        if (t == tt) mybal = bal;
    }
    __syncthreads();
    if (gi < n){
        int wo = 0;
        for (int w = 0; w < wave; w++) wo += whist[w][t];
        const unsigned long long below = (lane == 0) ? 0ULL : (~0ULL >> (64 - lane));
        const int rank = bhist[blockIdx.x * 8 + t] + wo + __popcll(mybal & below);
        sorted[rank] = gi;
    }
    __shared__ int sh[256];
    int v = (gi < n) ? ecnt[gi] : 0;
    __syncthreads();
    sh[tid] = v;
    __syncthreads();
    for (int off = 1; off < 256; off <<= 1){
        int tv = (tid >= off) ? sh[tid - off] : 0;
        __syncthreads();
        sh[tid] += tv;
        __syncthreads();
    }
    if (gi < n) eoff[gi] = sh[tid] - v;
    if (tid == 255) bsum[blockIdx.x] = sh[255];
}

// ---------------- weight fuse + MFMA-fragment pack + bias (fused) ----------------
// Column permutation: fragment (jg, lane) holds output feature
//   col = (jg>>2)*64 + (lane&15)*4 + (jg&3)
// so each C-fragment lane's 4 j-values are CONTIGUOUS bytes in the output row.
__global__ __launch_bounds__(256) void k_packbias(
    const float* __restrict__ Wq, const float* __restrict__ Wk, const float* __restrict__ Wv,
    const float* __restrict__ Wa, const float* __restrict__ Wm, const float* __restrict__ pri,
    const float* __restrict__ bq, const float* __restrict__ bk, const float* __restrict__ bv,
    unsigned short* __restrict__ pw, float* __restrict__ bpack)
{
    const int gid0 = blockIdx.x * 256 + threadIdx.x;
    if (gid0 < PACKN){
        const int gid = gid0;
        const int l = gid & 63;
        const int j = (gid >> 6) & 15;
        const int p = (gid >> 10) & 7;
        const int matg = gid >> 13;
        const int tn = matg / 7, m = matg % 7;
        const int col = (j >> 2) * 64 + (l & 15) * 4 + (j & 3);   // permuted mapping
        const int k0  = p * 32 + (l >> 4) * 8;
        const int h = col >> 5, c = col & 31;

        float vals[8];
        if (m == 0){
            #pragma unroll
            for (int i = 0; i < 8; i++)
                vals[i] = Wq[((size_t)tn * 256 + (k0 + i)) * 256 + col];
        } else if (m <= 3){
            const int te = m - 1;
            const float scale = 0.17677669529663687f * pri[te * H_ + h];
            #pragma unroll
            for (int i = 0; i < 8; i++){
                const float* wk = Wk + ((size_t)tn * 256 + (k0 + i)) * 256 + h * 32;
                const float* wa = Wa + (size_t)te * 1024 + c;
                float s = 0.f;
                for (int d = 0; d < 32; d++) s = fmaf(wk[d], wa[d * 32], s);
                vals[i] = s * scale;
            }
        } else {
            const int te = m - 4;
            #pragma unroll
            for (int i = 0; i < 8; i++){
                const float* wv = Wv + ((size_t)tn * 256 + (k0 + i)) * 256 + h * 32;
                const float* wm = Wm + (size_t)te * 1024 + c;
                float s = 0.f;
                for (int d = 0; d < 32; d++) s = fmaf(wv[d], wm[d * 32], s);
                vals[i] = s;
            }
        }
        unsigned short o[8];
        #pragma unroll
        for (int i = 0; i < 8; i++) o[i] = f2bf(vals[i]);
        *reinterpret_cast<uint4*>(pw + (size_t)gid * 8) = *reinterpret_cast<const uint4*>(o);
    } else if (gid0 < PACKN + BIASN){
        const int gid = gid0 - PACKN;
        const int col = gid & 255;
        const int matg = gid >> 8;
        const int tn = matg / 7, m = matg % 7;
        const int h = col >> 5, c = col & 31;
        float v;
        if (m == 0) v = bq[tn * 256 + col];
        else if (m <= 3){
            const int te = m - 1;
            float s = 0.f;
            for (int d = 0; d < 32; d++) s = fmaf(bk[tn * 256 + h * 32 + d], Wa[te * 1024 + d * 32 + c], s);
            v = s * 0.17677669529663687f * pri[te * H_ + h];
        } else {
            const int te = m - 4;
            float s = 0.f;
            for (int d = 0; d < 32; d++) s = fmaf(bv[tn * 256 + h * 32 + d], Wm[te * 1024 + d * 32 + c], s);
            v = s;
        }
        bpack[gid] = v;
    }
}

// ---------------- MFMA grouped projection (7 matrices; ALL outputs fp8, dword-packed) ----------------
__global__ __launch_bounds__(512, 2) void k_proj(
    const float* __restrict__ x, const int* __restrict__ sorted, const int* __restrict__ meta,
    const unsigned short* __restrict__ pw, const float* __restrict__ bpack,
    unsigned char* __restrict__ Qb, unsigned char* __restrict__ Ktb, unsigned char* __restrict__ Vtb)
{
    const int ntl = meta[0];
    if ((int)blockIdx.x >= ntl) return;
    const int q = ntl >> 3, r = ntl & 7;
    const int xcd = blockIdx.x & 7, ii = blockIdx.x >> 3;
    const int tile = (xcd < r) ? xcd * (q + 1) + ii
                               : r * (q + 1) + (xcd - r) * q + ii;
    const int tn    = meta[1 + 3*tile];
    const int start = meta[1 + 3*tile + 1];
    const int rows  = meta[1 + 3*tile + 2];

    __shared__ unsigned short xs[TROWS * 256];
    __shared__ int ids[TROWS];
    const int tid = threadIdx.x;
    if (tid < TROWS) ids[tid] = sorted[start + ((tid < rows) ? tid : 0)];
    __syncthreads();

    char* xb = reinterpret_cast<char*>(xs);
    for (int idx = tid; idx < TROWS * 32; idx += 512){
        const int r2 = idx >> 5, c16 = idx & 31;
        const float* src = x + (size_t)ids[r2] * DIM_ + c16 * 8;
        float4 a = *reinterpret_cast<const float4*>(src);
        float4 b = *reinterpret_cast<const float4*>(src + 4);
        unsigned short o[8] = {f2bf(a.x), f2bf(a.y), f2bf(a.z), f2bf(a.w),
                               f2bf(b.x), f2bf(b.y), f2bf(b.z), f2bf(b.w)};
        const int byte = r2 * 512 + ((c16 * 16) ^ ((r2 & 7) << 4));
        *reinterpret_cast<uint4*>(xb + byte) = *reinterpret_cast<const uint4*>(o);
    }
    __syncthreads();   // xs read-only from here on; NO barriers in the main loop

    const int wid = tid >> 6, l = tid & 63;
    const int rg = wid >> 2;
    const int cg = wid & 3;
    const int l15 = l & 15, lg = l >> 4;
    const int xorv = (l15 & 7) << 4;
    const size_t matbase = (size_t)tn * 7;
    const int rowbase = rg * 64;

    f32x4 acc[4][4];
    short8v b0[4], b1[4];

    {
        const unsigned short* sp0 = pw + matbase * 8 * 8192;
        #pragma unroll
        for (int j = 0; j < 4; j++)
            b0[j] = *reinterpret_cast<const short8v*>(sp0 + (cg * 4 + j) * 512 + l * 8);
    }

    auto proj_step = [&](const int s, short8v (&cur)[4], short8v (&pf)[4]){
        const int m = s >> 3, p = s & 7;
        const int matg = (int)matbase + m;

        if (s + 1 < NSTEP){
            const unsigned short* sp = pw + (matbase * 8 + (s + 1)) * 8192;
            #pragma unroll
            for (int j = 0; j < 4; j++)
                pf[j] = *reinterpret_cast<const short8v*>(sp + (cg * 4 + j) * 512 + l * 8);
        }

        if (p == 0){
            #pragma unroll
            for (int j = 0; j < 4; j++){
                const float bj = bpack[matg * 256 + cg * 64 + l15 * 4 + j];
                #pragma unroll
                for (int i = 0; i < 4; i++) acc[i][j] = (f32x4){bj, bj, bj, bj};
            }
        }

        {
            short8v a[4];
            const int kb = (p * 64 + (lg << 4)) ^ xorv;
            #pragma unroll
            for (int i = 0; i < 4; i++)
                a[i] = *reinterpret_cast<const short8v*>(xb + (rowbase + i * 16 + l15) * 512 + kb);
            #pragma unroll
            for (int i = 0; i < 4; i++)
                #pragma unroll
                for (int j = 0; j < 4; j++)
                    acc[i][j] = __builtin_amdgcn_mfma_f32_16x16x32_bf16(a[i], cur[j], acc[i][j], 0, 0, 0);
        }

        if (p == 7){
            // epilogue: lane's 4 j-cols are contiguous -> pack 4 fp8 into one dword store
            #pragma unroll
            for (int i = 0; i < 4; i++){
                #pragma unroll
                for (int rr = 0; rr < 4; rr++){
                    const int row = rowbase + i * 16 + lg * 4 + rr;
                    if (row < rows){
                        const size_t node = (size_t)ids[row];
                        unsigned w = (unsigned)__builtin_amdgcn_cvt_pk_fp8_f32(
                            acc[i][0][rr], acc[i][1][rr], 0, false);
                        w = (unsigned)__builtin_amdgcn_cvt_pk_fp8_f32(
                            acc[i][2][rr], acc[i][3][rr], (int)w, true);
                        unsigned char* base;
                        if (m == 0)       base = Qb  + node * 256;
                        else if (m <= 3)  base = Ktb + node * 768 + (size_t)(m - 1) * 256;
                        else              base = Vtb + node * 768 + (size_t)(m - 4) * 256;
                        *reinterpret_cast<unsigned*>(base + cg * 64 + l15 * 4) = w;
                    }
                }
            }
        }
    };

    for (int s = 0; s < NSTEP; s += 2){
        proj_step(s,     b0, b1);
        proj_step(s + 1, b1, b0);
    }
}

// ---------------- remaining CSR scans ----------------
__global__ __launch_bounds__(256) void k_scan2(int* __restrict__ bsum, int nb){
    __shared__ int sh[MAXNB];
    const int tid = threadIdx.x;
    for (int i = tid; i < nb; i += 256) sh[i] = bsum[i];
    __syncthreads();
    if (tid == 0){
        int run = 0;
        for (int b = 0; b < nb; b++){ int c = sh[b]; sh[b] = run; run += c; }
    }
    __syncthreads();
    for (int i = tid; i < nb; i += 256) bsum[i] = sh[i];
}

__global__ __launch_bounds__(256) void k_scan3(int n, int E_, const int* __restrict__ bsum,
                                               int* __restrict__ eoff, int* __restrict__ cursor){
    const int gi = blockIdx.x * 256 + threadIdx.x;
    if (gi < n){
        int v = eoff[gi] + bsum[blockIdx.x];
        eoff[gi] = v;
        cursor[gi] = v;
    }
    if (gi == 0) eoff[n] = E_;
}

__global__ void k_escatter(const int* __restrict__ ei, const int* __restrict__ etyp, int E_,
                           int* __restrict__ cursor, int2* __restrict__ ep){
    int e = blockIdx.x * blockDim.x + threadIdx.x;
    if (e < E_){
        int tg = ei[E_ + e];
        int pos = atomicAdd(&cursor[tg], 1);
        ep[pos] = make_int2(ei[e] | (etyp[e] << 28), tg);
    }
}

// ---------------- scores: fp8 Kt x fp8 Q -> exp (bf16 SC) + per-(type,head) sum ----------------
__global__ __launch_bounds__(256) void k_score(
    const unsigned char* __restrict__ Ktb, const unsigned char* __restrict__ Qb,
    const int2* __restrict__ ep,
    unsigned short* __restrict__ SC, float* __restrict__ psum, int EH)
{
    const int tid = threadIdx.x;
    float s0 = 0.f, s1 = 0.f, s2 = 0.f;

    for (int idx = blockIdx.x * 256 + tid; idx < EH; idx += NBLK * 256){
        const int pos = idx >> 3, h = idx & 7;
        const int2 pr = ep[pos];
        const int s = pr.x & 0x0FFFFFFF, t = pr.x >> 28;
        const int tg = pr.y;
        const unsigned char* kp = Ktb + ((size_t)s * 3 + t) * 256 + h * 32;   // 32 fp8
        const unsigned char* qp = Qb + (size_t)tg * 256 + h * 32;             // 32 fp8
        uint4 k8a = *reinterpret_cast<const uint4*>(kp);
        uint4 k8b = *reinterpret_cast<const uint4*>(kp + 16);
        unsigned kw[8] = {k8a.x, k8a.y, k8a.z, k8a.w, k8b.x, k8b.y, k8b.z, k8b.w};
        uint4 q8a = *reinterpret_cast<const uint4*>(qp);
        uint4 q8b = *reinterpret_cast<const uint4*>(qp + 16);
        unsigned qw[8] = {q8a.x, q8a.y, q8a.z, q8a.w, q8b.x, q8b.y, q8b.z, q8b.w};
        float acc = 0.f;
        #pragma unroll
        for (int w = 0; w < 8; w++){
            f32x2 klo = __builtin_amdgcn_cvt_pk_f32_fp8(kw[w], false);
            f32x2 khi = __builtin_amdgcn_cvt_pk_f32_fp8(kw[w], true);
            f32x2 qlo = __builtin_amdgcn_cvt_pk_f32_fp8(qw[w], false);
            f32x2 qhi = __builtin_amdgcn_cvt_pk_f32_fp8(qw[w], true);
            acc = fmaf(klo.x, qlo.x, acc);
            acc = fmaf(klo.y, qlo.y, acc);
            acc = fmaf(khi.x, qhi.x, acc);
            acc = fmaf(khi.y, qhi.y, acc);
        }
        const float e = __expf(acc);
        SC[idx] = f2bf(e);
        s0 += (t == 0) ? e : 0.f;
        s1 += (t == 1) ? e : 0.f;
        s2 += (t == 2) ? e : 0.f;
    }

    #pragma unroll
    for (int s = 8; s <= 32; s <<= 1){
        s0 += __shfl_xor(s0, s, 64);
        s1 += __shfl_xor(s1, s, 64);
        s2 += __shfl_xor(s2, s, 64);
    }
    __shared__ float sm[4][NBIN];
    const int wave = tid >> 6, lane = tid & 63;
    if (lane < 8){ sm[wave][lane] = s0; sm[wave][8 + lane] = s1; sm[wave][16 + lane] = s2; }
    __syncthreads();
    if (tid < NBIN)
        psum[blockIdx.x * NBIN + tid] = sm[0][tid] + sm[1][tid] + sm[2][tid] + sm[3][tid];
}

__global__ __launch_bounds__(256) void k_redsum(const float* __restrict__ psum,
                                                float* __restrict__ rw){
    const int b = blockIdx.x, tid = threadIdx.x;
    float s = 0.f;
    for (int i = tid; i < NBLK; i += 256) s += psum[i * NBIN + b];
    #pragma unroll
    for (int m = 1; m < 64; m <<= 1) s += __shfl_xor(s, m, 64);
    __shared__ float sm[4];
    if ((tid & 63) == 0) sm[tid >> 6] = s;
    __syncthreads();
    if (tid == 0){
        float t = sm[0] + sm[1] + sm[2] + sm[3];
        rw[b] = (t > 0.f) ? 1.f / t : 0.f;
    }
}

// ---------------- gather aggregation (fp8 Vt, thread per (tg,h)) + skip + LN ----------------
__global__ __launch_bounds__(256) void k_aggln(
    const unsigned char* __restrict__ Vtb, const float* __restrict__ x,
    const int* __restrict__ eoff, const int2* __restrict__ ep,
    const unsigned short* __restrict__ SC, const float* __restrict__ rw,
    const float* __restrict__ g, const float* __restrict__ b,
    float* __restrict__ out, int n)
{
    const int idx = blockIdx.x * 256 + threadIdx.x;
    if (idx >= n * H_) return;
    const int tg = idx >> 3, h = idx & 7;

    const float rw0 = rw[h], rw1 = rw[8 + h], rw2 = rw[16 + h];

    float acc[DK_];
    #pragma unroll
    for (int k = 0; k < DK_; k++) acc[k] = 0.f;

    const int p1 = eoff[tg + 1];
    for (int pos = eoff[tg]; pos < p1; ++pos){
        const int pl = ep[pos].x;
        const int s = pl & 0x0FFFFFFF, t = pl >> 28;
        const float rwv = (t == 0) ? rw0 : (t == 1) ? rw1 : rw2;
        const float w = bf2f(SC[(size_t)pos * 8 + h]) * rwv;
        const unsigned char* vp = Vtb + ((size_t)s * 3 + t) * 256 + h * 32;  // 32 fp8
        uint4 v8a = *reinterpret_cast<const uint4*>(vp);
        uint4 v8b = *reinterpret_cast<const uint4*>(vp + 16);
        unsigned vw[8] = {v8a.x, v8a.y, v8a.z, v8a.w, v8b.x, v8b.y, v8b.z, v8b.w};
        #pragma unroll
        for (int q = 0; q < 8; q++){
            f32x2 lo = __builtin_amdgcn_cvt_pk_f32_fp8(vw[q], false);
            f32x2 hi = __builtin_amdgcn_cvt_pk_f32_fp8(vw[q], true);
            acc[4*q+0] = fmaf(w, lo.x, acc[4*q+0]);
            acc[4*q+1] = fmaf(w, lo.y, acc[4*q+1]);
            acc[4*q+2] = fmaf(w, hi.x, acc[4*q+2]);
            acc[4*q+3] = fmaf(w, hi.y, acc[4*q+3]);
        }
    }

    #pragma unroll
    for (int k4 = 0; k4 < 8; k4++){
        float4 x4 = *reinterpret_cast<const float4*>(x + (size_t)tg * DIM_ + h * DK_ + k4 * 4);
        acc[4*k4] += x4.x; acc[4*k4+1] += x4.y; acc[4*k4+2] += x4.z; acc[4*k4+3] += x4.w;
    }

    float s1 = 0.f, s2 = 0.f;
    #pragma unroll
    for (int k = 0; k < DK_; k++){ s1 += acc[k]; s2 = fmaf(acc[k], acc[k], s2); }
    #pragma unroll
    for (int m = 1; m <= 4; m <<= 1){
        s1 += __shfl_xor(s1, m, 64);
        s2 += __shfl_xor(s2, m, 64);
    }
    const float mu  = s1 * (1.f / DIM_);
    const float var = s2 * (1.f / DIM_) - mu * mu;
    const float rs  = rsqrtf(var + LN_EPS);

    float* __restrict__ o = out + (size_t)tg * DIM_ + h * DK_;
    #pragma unroll
    for (int k4 = 0; k4 < 8; k4++){
        float4 g4 = *reinterpret_cast<const float4*>(g + h * DK_ + k4 * 4);
        float4 b4 = *reinterpret_cast<const float4*>(b + h * DK_ + k4 * 4);
        float4 o4;
        o4.x = (acc[4*k4]   - mu) * rs * g4.x + b4.x;
        o4.y = (acc[4*k4+1] - mu) * rs * g4.y + b4.y;
        o4.z = (acc[4*k4+2] - mu) * rs * g4.z + b4.z;
        o4.w = (acc[4*k4+3] - mu) * rs * g4.w + b4.w;
        *reinterpret_cast<float4*>(o + k4 * 4) = o4;
    }
}

extern "C" void kernel_launch(void* const* d_in, const int* in_sizes, int n_in,
                              void* d_out, int out_size, void* d_ws, size_t ws_size,
                              hipStream_t stream)
{
    const float* x   = (const float*)d_in[0];
    const int*  ei   = (const int*)d_in[1];
    const int*  ntyp = (const int*)d_in[3];
    const int*  etyp = (const int*)d_in[4];
    const float* Wk  = (const float*)d_in[5];
    const float* bk  = (const float*)d_in[6];
    const float* Wq  = (const float*)d_in[7];
    const float* bq  = (const float*)d_in[8];
    const float* Wv  = (const float*)d_in[9];
    const float* bv  = (const float*)d_in[10];
    const float* pri = (const float*)d_in[11];
    const float* Wa  = (const float*)d_in[12];
    const float* Wm  = (const float*)d_in[13];
    const float* lg  = (const float*)d_in[14];
    const float* lb  = (const float*)d_in[15];

    const int n  = in_sizes[0] / DIM_;
    const int E_ = in_sizes[4];
    const int EH = E_ * H_;
    float* out = (float*)d_out;

    // ---- workspace layout ----
    const size_t NF = (size_t)n * DIM_;
    unsigned char*  Qb  = (unsigned char*)d_ws;           // n*256 fp8 (raw Q)
    unsigned char*  Ktb = Qb + NF;                        // n*3*256 fp8 (K @ Wa[t], scaled)
    unsigned char*  Vtb = Ktb + NF * 3;                   // n*3*256 fp8 (V @ Wm[t])
    unsigned short* pwp = (unsigned short*)(Vtb + NF * 3);// NMATS*65536 bf16
    unsigned short* SC  = pwp + (size_t)NMATS * 65536;    // E*8 bf16 (CSR order, exp'd)
    float* bpack = (float*)(SC + (size_t)EH);             // NMATS*256
    float* psum  = bpack + NMATS * 256;                   // NBLK*24
    float* rw    = psum + (size_t)NBLK * NBIN;            // 24
    int* sorted  = (int*)(rw + NBIN);                     // n
    int* offsN   = sorted + n;                            // 8
    const int NB = (n + 255) / 256;
    int* bhist   = offsN + 8;                             // NB*8
    int* meta    = bhist + (size_t)NB * 8;                // 1 + 3*maxtiles
    const int maxtiles = (n + TROWS - 1) / TROWS + NT_;
    int* ecnt    = meta + 1 + 3 * maxtiles;               // n
    int* eoff    = ecnt + n;                              // n + 1
    int* cursorE = eoff + n + 1;                          // n
    int* bsum    = cursorE + n;                           // <= 1024
    int2* ep     = (int2*)(bsum + 1024);                  // E (payload, tgt)

    hipMemsetAsync(ecnt, 0, (size_t)n * sizeof(int), stream);

    // weight fuse/pack + bias (fused)
    k_packbias<<<(PACKN + BIASN + 255) / 256, 256, 0, stream>>>(
        Wq, Wk, Wv, Wa, Wm, pri, bq, bk, bv, pwp, bpack);

    // node hist + edge count (fused) -> scans -> scatter
    k_histcount<<<ESB, 256, 0, stream>>>(ntyp, n, bhist, NB, ei, E_, ecnt);
    k_scanhist <<<1, 256, 0, stream>>>(bhist, NB, offsN, meta);
    k_scatscan <<<NB, 256, 0, stream>>>(ntyp, n, bhist, sorted, ecnt, eoff, bsum);
    k_scan2    <<<1, 256, 0, stream>>>(bsum, NB);
    k_scan3    <<<NB, 256, 0, stream>>>(n, E_, bsum, eoff, cursorE);

    // fused MFMA projections
    k_proj<<<maxtiles, 512, 0, stream>>>(x, sorted, meta, pwp, bpack, Qb, Ktb, Vtb);

    // edge scatter -> CSR-ordered scores -> denominators -> gather-aggregate + LN
    k_escatter<<<(E_ + 255) / 256, 256, 0, stream>>>(ei, etyp, E_, cursorE, ep);
    k_score   <<<NBLK, 256, 0, stream>>>(Ktb, Qb, ep, SC, psum, EH);
    k_redsum  <<<NBIN, 256, 0, stream>>>(psum, rw);
    k_aggln   <<<(n * H_ + 255) / 256, 256, 0, stream>>>(Vtb, x, eoff, ep, SC, rw, lg, lb, out, n);
}

// Round 24
// 214.588 us; speedup vs baseline: 1.3002x; 1.0077x over previous
//
#include <hip/hip_runtime.h>
#include <math.h>

#define H_    8
#define DK_   32
#define NT_   6
#define ET_   3
#define DIM_  256
#define LN_EPS 1e-5f
#define NMATS (NT_ * 7)   // per node type: Q, Kt[0..2], Vt[0..2]
#define NBLK  2048        // grid-stride blocks for edge score pass
#define NBIN  (ET_ * H_)  // 24
#define NSTEP 56          // 7 matrices x 8 K-slabs
#define TROWS 128         // rows per projection tile
#define MAXNB 1024        // max 256-thread blocks over n
#define ESB   1024        // blocks for hist+count fused kernel
#define PACKN (NMATS * 8 * 16 * 64)
#define BIASN (NMATS * 256)

typedef __attribute__((ext_vector_type(4))) float f32x4;
typedef __attribute__((ext_vector_type(2))) float f32x2;
typedef long long i64;

__device__ __forceinline__ unsigned short f2bf(float f){
    unsigned u = __float_as_uint(f);
    return (unsigned short)((u + 0x7fffu + ((u >> 16) & 1u)) >> 16);
}
__device__ __forceinline__ float bf2f(unsigned short v){ return __uint_as_float((unsigned)v << 16); }

// ---------------- node hist + edge target count (fused) ----------------
__global__ __launch_bounds__(256) void k_histcount(
    const int* __restrict__ ntyp, int n, int* __restrict__ bhist, int nb,
    const int* __restrict__ ei, int E_, int* __restrict__ ecnt)
{
    const int tid = threadIdx.x;
    if ((int)blockIdx.x < nb){
        const int gi = blockIdx.x * 256 + tid;
        const int wave = tid >> 6, lane = tid & 63;
        const int t = (gi < n) ? ntyp[gi] : -1;
        __shared__ int whist[4][8];
        #pragma unroll
        for (int tt = 0; tt < NT_; tt++){
            unsigned long long bal = __ballot(t == tt);
            if (lane == 0) whist[wave][tt] = __popcll(bal);
        }
        __syncthreads();
        if (tid < NT_)
            bhist[blockIdx.x * 8 + tid] =
                whist[0][tid] + whist[1][tid] + whist[2][tid] + whist[3][tid];
    }
    for (int e = blockIdx.x * 256 + tid; e < E_; e += ESB * 256)
        atomicAdd(&ecnt[ei[E_ + e]], 1);
}

// single block; ALL dependent chains run against LDS, never global.
__global__ __launch_bounds__(256) void k_scanhist(int* __restrict__ bhist, int nb,
                                                  int* __restrict__ offs, int* __restrict__ meta){
    __shared__ int hh[MAXNB * 8 / 4];
    __shared__ int tot[8], toff[8], tbase[8], ntl_s;
    const int tid = threadIdx.x;

    for (int i = tid; i < nb * 8; i += 256) hh[i] = bhist[i];
    __syncthreads();

    if (tid < 8){
        int run = 0;
        for (int b = 0; b < nb; b++){
            int c = hh[b * 8 + tid];
            hh[b * 8 + tid] = run;
            run += c;
        }
        tot[tid] = run;
    }
    __syncthreads();

    if (tid == 0){
        int off = 0, tb = 0;
        for (int tt = 0; tt < NT_; tt++){
            toff[tt] = off;
            tbase[tt] = tb;
            tb += (tot[tt] + TROWS - 1) / TROWS;
            off += tot[tt];
        }
        for (int tt = NT_; tt < 8; tt++){ toff[tt] = 0; tbase[tt] = tb; }
        ntl_s = tb;
        meta[0] = tb;
    }
    __syncthreads();

    for (int i = tid; i < ntl_s; i += 256){
        int t = 0;
        #pragma unroll
        for (int tt = 1; tt < NT_; tt++) if (i >= tbase[tt]) t = tt;
        const int k = i - tbase[t];
        const int rem = tot[t] - k * TROWS;
        meta[1 + 3*i]     = t;
        meta[1 + 3*i + 1] = toff[t] + k * TROWS;
        meta[1 + 3*i + 2] = (rem < TROWS) ? rem : TROWS;
    }
    if (tid < NT_) offs[tid] = toff[tid];

    for (int i = tid; i < nb * 8; i += 256)
        bhist[i] = hh[i] + toff[i & 7];
}

// node rank-scatter + edge-count block scan (fused)
__global__ __launch_bounds__(256) void k_scatscan(
    const int* __restrict__ ntyp, int n, const int* __restrict__ bhist,
    int* __restrict__ sorted,
    const int* __restrict__ ecnt, int* __restrict__ eoff, int* __restrict__ bsum)
{
    const int tid = threadIdx.x;
    const int gi = blockIdx.x * 256 + tid;
    const int wave = tid >> 6, lane = tid & 63;
    const int t = (gi < n) ? ntyp[gi] : -1;
    __shared__ int whist[4][8];
    unsigned long long mybal = 0;
    #pragma unroll
    for (int tt = 0; tt < NT_; tt++){
        unsigned long long bal = __ballot(t == tt);
        if (lane == 0) whist[wave][tt] = __popcll(bal);
        if (t == tt) mybal = bal;
    }
    __syncthreads();
    if (gi < n){
        int wo = 0;
        for (int w = 0; w < wave; w++) wo += whist[w][t];
        const unsigned long long below = (lane == 0) ? 0ULL : (~0ULL >> (64 - lane));
        const int rank = bhist[blockIdx.x * 8 + t] + wo + __popcll(mybal & below);
        sorted[rank] = gi;
    }
    __shared__ int sh[256];
    int v = (gi < n) ? ecnt[gi] : 0;
    __syncthreads();
    sh[tid] = v;
    __syncthreads();
    for (int off = 1; off < 256; off <<= 1){
        int tv = (tid >= off) ? sh[tid - off] : 0;
        __syncthreads();
        sh[tid] += tv;
        __syncthreads();
    }
    if (gi < n) eoff[gi] = sh[tid] - v;
    if (tid == 255) bsum[blockIdx.x] = sh[255];
}

// ---------------- weight fuse + fp8 MFMA-fragment pack + bias (fused) ----------------
// Column permutation: fragment (jg, lane) holds output feature
//   col = (jg>>2)*64 + (lane&15)*4 + (jg&3)
// pw layout: [matg][p(8)][jg(16)][lane(64)] -> 8 fp8 bytes (K elems i=0..7)
__global__ __launch_bounds__(256) void k_packbias(
    const float* __restrict__ Wq, const float* __restrict__ Wk, const float* __restrict__ Wv,
    const float* __restrict__ Wa, const float* __restrict__ Wm, const float* __restrict__ pri,
    const float* __restrict__ bq, const float* __restrict__ bk, const float* __restrict__ bv,
    unsigned char* __restrict__ pw, float* __restrict__ bpack)
{
    const int gid0 = blockIdx.x * 256 + threadIdx.x;
    if (gid0 < PACKN){
        const int gid = gid0;
        const int l = gid & 63;
        const int j = (gid >> 6) & 15;
        const int p = (gid >> 10) & 7;
        const int matg = gid >> 13;
        const int tn = matg / 7, m = matg % 7;
        const int col = (j >> 2) * 64 + (l & 15) * 4 + (j & 3);   // permuted mapping
        const int k0  = p * 32 + (l >> 4) * 8;
        const int h = col >> 5, c = col & 31;

        float vals[8];
        if (m == 0){
            #pragma unroll
            for (int i = 0; i < 8; i++)
                vals[i] = Wq[((size_t)tn * 256 + (k0 + i)) * 256 + col];
        } else if (m <= 3){
            const int te = m - 1;
            const float scale = 0.17677669529663687f * pri[te * H_ + h];
            #pragma unroll
            for (int i = 0; i < 8; i++){
                const float* wk = Wk + ((size_t)tn * 256 + (k0 + i)) * 256 + h * 32;
                const float* wa = Wa + (size_t)te * 1024 + c;
                float s = 0.f;
                for (int d = 0; d < 32; d++) s = fmaf(wk[d], wa[d * 32], s);
                vals[i] = s * scale;
            }
        } else {
            const int te = m - 4;
            #pragma unroll
            for (int i = 0; i < 8; i++){
                const float* wv = Wv + ((size_t)tn * 256 + (k0 + i)) * 256 + h * 32;
                const float* wm = Wm + (size_t)te * 1024 + c;
                float s = 0.f;
                for (int d = 0; d < 32; d++) s = fmaf(wv[d], wm[d * 32], s);
                vals[i] = s;
            }
        }
        unsigned w0 = (unsigned)__builtin_amdgcn_cvt_pk_fp8_f32(vals[0], vals[1], 0, false);
        w0 = (unsigned)__builtin_amdgcn_cvt_pk_fp8_f32(vals[2], vals[3], (int)w0, true);
        unsigned w1 = (unsigned)__builtin_amdgcn_cvt_pk_fp8_f32(vals[4], vals[5], 0, false);
        w1 = (unsigned)__builtin_amdgcn_cvt_pk_fp8_f32(vals[6], vals[7], (int)w1, true);
        *reinterpret_cast<uint2*>(pw + (size_t)gid * 8) = make_uint2(w0, w1);
    } else if (gid0 < PACKN + BIASN){
        const int gid = gid0 - PACKN;
        const int col = gid & 255;
        const int matg = gid >> 8;
        const int tn = matg / 7, m = matg % 7;
        const int h = col >> 5, c = col & 31;
        float v;
        if (m == 0) v = bq[tn * 256 + col];
        else if (m <= 3){
            const int te = m - 1;
            float s = 0.f;
            for (int d = 0; d < 32; d++) s = fmaf(bk[tn * 256 + h * 32 + d], Wa[te * 1024 + d * 32 + c], s);
            v = s * 0.17677669529663687f * pri[te * H_ + h];
        } else {
            const int te = m - 4;
            float s = 0.f;
            for (int d = 0; d < 32; d++) s = fmaf(bv[tn * 256 + h * 32 + d], Wm[te * 1024 + d * 32 + c], s);
            v = s;
        }
        bpack[gid] = v;
    }
}

// ---------------- fp8 MFMA grouped projection (7 matrices; outputs fp8, dword-packed) ----------------
__global__ __launch_bounds__(512, 2) void k_proj(
    const float* __restrict__ x, const int* __restrict__ sorted, const int* __restrict__ meta,
    const unsigned char* __restrict__ pw, const float* __restrict__ bpack,
    unsigned char* __restrict__ Qb, unsigned char* __restrict__ Ktb, unsigned char* __restrict__ Vtb)
{
    const int ntl = meta[0];
    if ((int)blockIdx.x >= ntl) return;
    const int q = ntl >> 3, r = ntl & 7;
    const int xcd = blockIdx.x & 7, ii = blockIdx.x >> 3;
    const int tile = (xcd < r) ? xcd * (q + 1) + ii
                               : r * (q + 1) + (xcd - r) * q + ii;
    const int tn    = meta[1 + 3*tile];
    const int start = meta[1 + 3*tile + 1];
    const int rows  = meta[1 + 3*tile + 2];

    __shared__ unsigned char xs[TROWS * 256];   // 32 KB fp8 A-tile, XOR-swizzled
    __shared__ int ids[TROWS];
    const int tid = threadIdx.x;
    if (tid < TROWS) ids[tid] = sorted[start + ((tid < rows) ? tid : 0)];
    __syncthreads();

    char* xb = reinterpret_cast<char*>(xs);
    for (int idx = tid; idx < TROWS * 32; idx += 512){
        const int r2 = idx >> 5, c8 = idx & 31;
        const float* src = x + (size_t)ids[r2] * DIM_ + c8 * 8;
        float4 a = *reinterpret_cast<const float4*>(src);
        float4 b = *reinterpret_cast<const float4*>(src + 4);
        unsigned w0 = (unsigned)__builtin_amdgcn_cvt_pk_fp8_f32(a.x, a.y, 0, false);
        w0 = (unsigned)__builtin_amdgcn_cvt_pk_fp8_f32(a.z, a.w, (int)w0, true);
        unsigned w1 = (unsigned)__builtin_amdgcn_cvt_pk_fp8_f32(b.x, b.y, 0, false);
        w1 = (unsigned)__builtin_amdgcn_cvt_pk_fp8_f32(b.z, b.w, (int)w1, true);
        const int byte = r2 * 256 + ((c8 * 8) ^ ((r2 & 7) << 3));
        *reinterpret_cast<uint2*>(xb + byte) = make_uint2(w0, w1);
    }
    __syncthreads();   // xs read-only from here on; NO barriers in the main loop

    const int wid = tid >> 6, l = tid & 63;
    const int rg = wid >> 2;
    const int cg = wid & 3;
    const int l15 = l & 15, lg = l >> 4;
    const int xorv = (l15 & 7) << 3;
    const size_t matbase = (size_t)tn * 7;
    const int rowbase = rg * 64;

    f32x4 acc[4][4];
    i64 b0[4], b1[4];

    {
        const unsigned char* sp0 = pw + matbase * 8 * 8192;
        #pragma unroll
        for (int j = 0; j < 4; j++)
            b0[j] = *reinterpret_cast<const i64*>(sp0 + (cg * 4 + j) * 512 + l * 8);
    }

    auto proj_step = [&](const int s, i64 (&cur)[4], i64 (&pf)[4]){
        const int m = s >> 3, p = s & 7;
        const int matg = (int)matbase + m;

        if (s + 1 < NSTEP){
            const unsigned char* sp = pw + (matbase * 8 + (s + 1)) * 8192;
            #pragma unroll
            for (int j = 0; j < 4; j++)
                pf[j] = *reinterpret_cast<const i64*>(sp + (cg * 4 + j) * 512 + l * 8);
        }

        if (p == 0){
            #pragma unroll
            for (int j = 0; j < 4; j++){
                const float bj = bpack[matg * 256 + cg * 64 + l15 * 4 + j];
                #pragma unroll
                for (int i = 0; i < 4; i++) acc[i][j] = (f32x4){bj, bj, bj, bj};
            }
        }

        {
            i64 a[4];
            const int kb = (p * 32 + (lg << 3)) ^ xorv;
            #pragma unroll
            for (int i = 0; i < 4; i++)
                a[i] = *reinterpret_cast<const i64*>(xb + (rowbase + i * 16 + l15) * 256 + kb);
            #pragma unroll
            for (int i = 0; i < 4; i++)
                #pragma unroll
                for (int j = 0; j < 4; j++)
                    acc[i][j] = __builtin_amdgcn_mfma_f32_16x16x32_fp8_fp8(a[i], cur[j], acc[i][j], 0, 0, 0);
        }

        if (p == 7){
            // epilogue: lane's 4 j-cols are contiguous -> pack 4 fp8 into one dword store
            #pragma unroll
            for (int i = 0; i < 4; i++){
                #pragma unroll
                for (int rr = 0; rr < 4; rr++){
                    const int row = rowbase + i * 16 + lg * 4 + rr;
                    if (row < rows){
                        const size_t node = (size_t)ids[row];
                        unsigned w = (unsigned)__builtin_amdgcn_cvt_pk_fp8_f32(
                            acc[i][0][rr], acc[i][1][rr], 0, false);
                        w = (unsigned)__builtin_amdgcn_cvt_pk_fp8_f32(
                            acc[i][2][rr], acc[i][3][rr], (int)w, true);
                        unsigned char* base;
                        if (m == 0)       base = Qb  + node * 256;
                        else if (m <= 3)  base = Ktb + node * 768 + (size_t)(m - 1) * 256;
                        else              base = Vtb + node * 768 + (size_t)(m - 4) * 256;
                        *reinterpret_cast<unsigned*>(base + cg * 64 + l15 * 4) = w;
                    }
                }
            }
        }
    };

    for (int s = 0; s < NSTEP; s += 2){
        proj_step(s,     b0, b1);
        proj_step(s + 1, b1, b0);
    }
}

// ---------------- remaining CSR scans ----------------
__global__ __launch_bounds__(256) void k_scan2(int* __restrict__ bsum, int nb){
    __shared__ int sh[MAXNB];
    const int tid = threadIdx.x;
    for (int i = tid; i < nb; i += 256) sh[i] = bsum[i];
    __syncthreads();
    if (tid == 0){
        int run = 0;
        for (int b = 0; b < nb; b++){ int c = sh[b]; sh[b] = run; run += c; }
    }
    __syncthreads();
    for (int i = tid; i < nb; i += 256) bsum[i] = sh[i];
}

__global__ __launch_bounds__(256) void k_scan3(int n, int E_, const int* __restrict__ bsum,
                                               int* __restrict__ eoff, int* __restrict__ cursor){
    const int gi = blockIdx.x * 256 + threadIdx.x;
    if (gi < n){
        int v = eoff[gi] + bsum[blockIdx.x];
        eoff[gi] = v;
        cursor[gi] = v;
    }
    if (gi == 0) eoff[n] = E_;
}

__global__ void k_escatter(const int* __restrict__ ei, const int* __restrict__ etyp, int E_,
                           int* __restrict__ cursor, int2* __restrict__ ep){
    int e = blockIdx.x * blockDim.x + threadIdx.x;
    if (e < E_){
        int tg = ei[E_ + e];
        int pos = atomicAdd(&cursor[tg], 1);
        ep[pos] = make_int2(ei[e] | (etyp[e] << 28), tg);
    }
}

// ---------------- scores: fp8 Kt x fp8 Q -> exp (bf16 SC) + per-(type,head) sum ----------------
__global__ __launch_bounds__(256) void k_score(
    const unsigned char* __restrict__ Ktb, const unsigned char* __restrict__ Qb,
    const int2* __restrict__ ep,
    unsigned short* __restrict__ SC, float* __restrict__ psum, int EH)
{
    const int tid = threadIdx.x;
    float s0 = 0.f, s1 = 0.f, s2 = 0.f;

    for (int idx = blockIdx.x * 256 + tid; idx < EH; idx += NBLK * 256){
        const int pos = idx >> 3, h = idx & 7;
        const int2 pr = ep[pos];
        const int s = pr.x & 0x0FFFFFFF, t = pr.x >> 28;
        const int tg = pr.y;
        const unsigned char* kp = Ktb + ((size_t)s * 3 + t) * 256 + h * 32;   // 32 fp8
        const unsigned char* qp = Qb + (size_t)tg * 256 + h * 32;             // 32 fp8
        uint4 k8a = *reinterpret_cast<const uint4*>(kp);
        uint4 k8b = *reinterpret_cast<const uint4*>(kp + 16);
        unsigned kw[8] = {k8a.x, k8a.y, k8a.z, k8a.w, k8b.x, k8b.y, k8b.z, k8b.w};
        uint4 q8a = *reinterpret_cast<const uint4*>(qp);
        uint4 q8b = *reinterpret_cast<const uint4*>(qp + 16);
        unsigned qw[8] = {q8a.x, q8a.y, q8a.z, q8a.w, q8b.x, q8b.y, q8b.z, q8b.w};
        float acc = 0.f;
        #pragma unroll
        for (int w = 0; w < 8; w++){
            f32x2 klo = __builtin_amdgcn_cvt_pk_f32_fp8(kw[w], false);
            f32x2 khi = __builtin_amdgcn_cvt_pk_f32_fp8(kw[w], true);
            f32x2 qlo = __builtin_amdgcn_cvt_pk_f32_fp8(qw[w], false);
            f32x2 qhi = __builtin_amdgcn_cvt_pk_f32_fp8(qw[w], true);
            acc = fmaf(klo.x, qlo.x, acc);
            acc = fmaf(klo.y, qlo.y, acc);
            acc = fmaf(khi.x, qhi.x, acc);
            acc = fmaf(khi.y, qhi.y, acc);
        }
        const float e = __expf(acc);
        SC[idx] = f2bf(e);
        s0 += (t == 0) ? e : 0.f;
        s1 += (t == 1) ? e : 0.f;
        s2 += (t == 2) ? e : 0.f;
    }

    #pragma unroll
    for (int s = 8; s <= 32; s <<= 1){
        s0 += __shfl_xor(s0, s, 64);
        s1 += __shfl_xor(s1, s, 64);
        s2 += __shfl_xor(s2, s, 64);
    }
    __shared__ float sm[4][NBIN];
    const int wave = tid >> 6, lane = tid & 63;
    if (lane < 8){ sm[wave][lane] = s0; sm[wave][8 + lane] = s1; sm[wave][16 + lane] = s2; }
    __syncthreads();
    if (tid < NBIN)
        psum[blockIdx.x * NBIN + tid] = sm[0][tid] + sm[1][tid] + sm[2][tid] + sm[3][tid];
}

__global__ __launch_bounds__(256) void k_redsum(const float* __restrict__ psum,
                                                float* __restrict__ rw){
    const int b = blockIdx.x, tid = threadIdx.x;
    float s = 0.f;
    for (int i = tid; i < NBLK; i += 256) s += psum[i * NBIN + b];
    #pragma unroll
    for (int m = 1; m < 64; m <<= 1) s += __shfl_xor(s, m, 64);
    __shared__ float sm[4];
    if ((tid & 63) == 0) sm[tid >> 6] = s;
    __syncthreads();
    if (tid == 0){
        float t = sm[0] + sm[1] + sm[2] + sm[3];
        rw[b] = (t > 0.f) ? 1.f / t : 0.f;
    }
}

// ---------------- gather aggregation (fp8 Vt, thread per (tg,h)) + skip + LN ----------------
__global__ __launch_bounds__(256) void k_aggln(
    const unsigned char* __restrict__ Vtb, const float* __restrict__ x,
    const int* __restrict__ eoff, const int2* __restrict__ ep,
    const unsigned short* __restrict__ SC, const float* __restrict__ rw,
    const float* __restrict__ g, const float* __restrict__ b,
    float* __restrict__ out, int n)
{
    const int idx = blockIdx.x * 256 + threadIdx.x;
    if (idx >= n * H_) return;
    const int tg = idx >> 3, h = idx & 7;

    const float rw0 = rw[h], rw1 = rw[8 + h], rw2 = rw[16 + h];

    float acc[DK_];
    #pragma unroll
    for (int k = 0; k < DK_; k++) acc[k] = 0.f;

    const int p1 = eoff[tg + 1];
    for (int pos = eoff[tg]; pos < p1; ++pos){
        const int pl = ep[pos].x;
        const int s = pl & 0x0FFFFFFF, t = pl >> 28;
        const float rwv = (t == 0) ? rw0 : (t == 1) ? rw1 : rw2;
        const float w = bf2f(SC[(size_t)pos * 8 + h]) * rwv;
        const unsigned char* vp = Vtb + ((size_t)s * 3 + t) * 256 + h * 32;  // 32 fp8
        uint4 v8a = *reinterpret_cast<const uint4*>(vp);
        uint4 v8b = *reinterpret_cast<const uint4*>(vp + 16);
        unsigned vw[8] = {v8a.x, v8a.y, v8a.z, v8a.w, v8b.x, v8b.y, v8b.z, v8b.w};
        #pragma unroll
        for (int q = 0; q < 8; q++){
            f32x2 lo = __builtin_amdgcn_cvt_pk_f32_fp8(vw[q], false);
            f32x2 hi = __builtin_amdgcn_cvt_pk_f32_fp8(vw[q], true);
            acc[4*q+0] = fmaf(w, lo.x, acc[4*q+0]);
            acc[4*q+1] = fmaf(w, lo.y, acc[4*q+1]);
            acc[4*q+2] = fmaf(w, hi.x, acc[4*q+2]);
            acc[4*q+3] = fmaf(w, hi.y, acc[4*q+3]);
        }
    }

    #pragma unroll
    for (int k4 = 0; k4 < 8; k4++){
        float4 x4 = *reinterpret_cast<const float4*>(x + (size_t)tg * DIM_ + h * DK_ + k4 * 4);
        acc[4*k4] += x4.x; acc[4*k4+1] += x4.y; acc[4*k4+2] += x4.z; acc[4*k4+3] += x4.w;
    }

    float s1 = 0.f, s2 = 0.f;
    #pragma unroll
    for (int k = 0; k < DK_; k++){ s1 += acc[k]; s2 = fmaf(acc[k], acc[k], s2); }
    #pragma unroll
    for (int m = 1; m <= 4; m <<= 1){
        s1 += __shfl_xor(s1, m, 64);
        s2 += __shfl_xor(s2, m, 64);
    }
    const float mu  = s1 * (1.f / DIM_);
    const float var = s2 * (1.f / DIM_) - mu * mu;
    const float rs  = rsqrtf(var + LN_EPS);

    float* __restrict__ o = out + (size_t)tg * DIM_ + h * DK_;
    #pragma unroll
    for (int k4 = 0; k4 < 8; k4++){
        float4 g4 = *reinterpret_cast<const float4*>(g + h * DK_ + k4 * 4);
        float4 b4 = *reinterpret_cast<const float4*>(b + h * DK_ + k4 * 4);
        float4 o4;
        o4.x = (acc[4*k4]   - mu) * rs * g4.x + b4.x;
        o4.y = (acc[4*k4+1] - mu) * rs * g4.y + b4.y;
        o4.z = (acc[4*k4+2] - mu) * rs * g4.z + b4.z;
        o4.w = (acc[4*k4+3] - mu) * rs * g4.w + b4.w;
        *reinterpret_cast<float4*>(o + k4 * 4) = o4;
    }
}

extern "C" void kernel_launch(void* const* d_in, const int* in_sizes, int n_in,
                              void* d_out, int out_size, void* d_ws, size_t ws_size,
                              hipStream_t stream)
{
    const float* x   = (const float*)d_in[0];
    const int*  ei   = (const int*)d_in[1];
    const int*  ntyp = (const int*)d_in[3];
    const int*  etyp = (const int*)d_in[4];
    const float* Wk  = (const float*)d_in[5];
    const float* bk  = (const float*)d_in[6];
    const float* Wq  = (const float*)d_in[7];
    const float* bq  = (const float*)d_in[8];
    const float* Wv  = (const float*)d_in[9];
    const float* bv  = (const float*)d_in[10];
    const float* pri = (const float*)d_in[11];
    const float* Wa  = (const float*)d_in[12];
    const float* Wm  = (const float*)d_in[13];
    const float* lg  = (const float*)d_in[14];
    const float* lb  = (const float*)d_in[15];

    const int n  = in_sizes[0] / DIM_;
    const int E_ = in_sizes[4];
    const int EH = E_ * H_;
    float* out = (float*)d_out;

    // ---- workspace layout ----
    const size_t NF = (size_t)n * DIM_;
    unsigned char*  Qb  = (unsigned char*)d_ws;           // n*256 fp8 (raw Q)
    unsigned char*  Ktb = Qb + NF;                        // n*3*256 fp8 (K @ Wa[t], scaled)
    unsigned char*  Vtb = Ktb + NF * 3;                   // n*3*256 fp8 (V @ Wm[t])
    unsigned char*  pwp = Vtb + NF * 3;                   // NMATS*65536 bytes (fp8 fragments)
    unsigned short* SC  = (unsigned short*)(pwp + (size_t)NMATS * 65536); // E*8 bf16
    float* bpack = (float*)(SC + (size_t)EH);             // NMATS*256
    float* psum  = bpack + NMATS * 256;                   // NBLK*24
    float* rw    = psum + (size_t)NBLK * NBIN;            // 24
    int* sorted  = (int*)(rw + NBIN);                     // n
    int* offsN   = sorted + n;                            // 8
    const int NB = (n + 255) / 256;
    int* bhist   = offsN + 8;                             // NB*8
    int* meta    = bhist + (size_t)NB * 8;                // 1 + 3*maxtiles
    const int maxtiles = (n + TROWS - 1) / TROWS + NT_;
    int* ecnt    = meta + 1 + 3 * maxtiles;               // n
    int* eoff    = ecnt + n;                              // n + 1
    int* cursorE = eoff + n + 1;                          // n
    int* bsum    = cursorE + n;                           // <= 1024
    int2* ep     = (int2*)(bsum + 1024);                  // E (payload, tgt)

    hipMemsetAsync(ecnt, 0, (size_t)n * sizeof(int), stream);

    // weight fuse/pack + bias (fused)
    k_packbias<<<(PACKN + BIASN + 255) / 256, 256, 0, stream>>>(
        Wq, Wk, Wv, Wa, Wm, pri, bq, bk, bv, pwp, bpack);

    // node hist + edge count (fused) -> scans -> scatter
    k_histcount<<<ESB, 256, 0, stream>>>(ntyp, n, bhist, NB, ei, E_, ecnt);
    k_scanhist <<<1, 256, 0, stream>>>(bhist, NB, offsN, meta);
    k_scatscan <<<NB, 256, 0, stream>>>(ntyp, n, bhist, sorted, ecnt, eoff, bsum);
    k_scan2    <<<1, 256, 0, stream>>>(bsum, NB);
    k_scan3    <<<NB, 256, 0, stream>>>(n, E_, bsum, eoff, cursorE);

    // fused fp8-MFMA projections
    k_proj<<<maxtiles, 512, 0, stream>>>(x, sorted, meta, pwp, bpack, Qb, Ktb, Vtb);

    // edge scatter -> CSR-ordered scores -> denominators -> gather-aggregate + LN
    k_escatter<<<(E_ + 255) / 256, 256, 0, stream>>>(ei, etyp, E_, cursorE, ep);
    k_score   <<<NBLK, 256, 0, stream>>>(Ktb, Qb, ep, SC, psum, EH);
    k_redsum  <<<NBIN, 256, 0, stream>>>(psum, rw);
    k_aggln   <<<(n * H_ + 255) / 256, 256, 0, stream>>>(Vtb, x, eoff, ep, SC, rw, lg, lb, out, n);
}